// Round 1
// baseline (1194.029 us; speedup 1.0000x reference)
//
#include <hip/hip_runtime.h>
#include <math.h>

// Problem constants (fixed by the reference)
#define BN 16384
#define DN 512
#define KN 16384
#define HN 256
#define ZN 128

// ---------------------------------------------------------------------------
// Encoder: features[B,512] -> Linear(512,256) -> LN -> GELU -> Linear(256,128)
// writes encoded[B][128] fp32. Block = 256 threads, 8 rows per block.
// ---------------------------------------------------------------------------
__global__ __launch_bounds__(256) void enc_kernel(
    const float* __restrict__ feat, const float* __restrict__ W1, const float* __restrict__ b1,
    const float* __restrict__ g1, const float* __restrict__ be1,
    const float* __restrict__ W2, const float* __restrict__ b2,
    float* __restrict__ encoded)
{
    __shared__ float xf[8][512];
    __shared__ float hb[8][256];
    __shared__ float red1[4][8];
    __shared__ float red2[4][8];
    const int tid = threadIdx.x;
    const int rbase = blockIdx.x * 8;

    // stage 8 feature rows (contiguous 4096 fp32 = 16KB), coalesced float4
    {
        const float4* src = (const float4*)(feat + rbase * 512);
        float4* dst = (float4*)&xf[0][0];
        #pragma unroll
        for (int i = 0; i < 4; ++i) dst[tid * 4 + i] = src[tid * 4 + i];
    }
    __syncthreads();

    // GEMM1: t1[r][j], j = tid (H=256 columns)
    const int j = tid;
    float acc[8];
    {
        float bias = b1[j];
        #pragma unroll
        for (int r = 0; r < 8; ++r) acc[r] = bias;
    }
    for (int k = 0; k < 512; k += 4) {
        float w0 = W1[(k + 0) * 256 + j];
        float w1 = W1[(k + 1) * 256 + j];
        float w2 = W1[(k + 2) * 256 + j];
        float w3 = W1[(k + 3) * 256 + j];
        #pragma unroll
        for (int r = 0; r < 8; ++r) {
            float4 x = *((const float4*)&xf[r][k]);
            acc[r] = fmaf(x.x, w0, acc[r]);
            acc[r] = fmaf(x.y, w1, acc[r]);
            acc[r] = fmaf(x.z, w2, acc[r]);
            acc[r] = fmaf(x.w, w3, acc[r]);
        }
    }

    // LayerNorm over H=256 (block-wide reduction), then exact GELU
    float s1[8], s2[8];
    #pragma unroll
    for (int r = 0; r < 8; ++r) { s1[r] = acc[r]; s2[r] = acc[r] * acc[r]; }
    #pragma unroll
    for (int m = 1; m < 64; m <<= 1) {
        #pragma unroll
        for (int r = 0; r < 8; ++r) {
            s1[r] += __shfl_xor(s1[r], m, 64);
            s2[r] += __shfl_xor(s2[r], m, 64);
        }
    }
    const int wave = tid >> 6, lane = tid & 63;
    if (lane == 0) {
        #pragma unroll
        for (int r = 0; r < 8; ++r) { red1[wave][r] = s1[r]; red2[wave][r] = s2[r]; }
    }
    __syncthreads();
    {
        float gg = g1[j], bb = be1[j];
        #pragma unroll
        for (int r = 0; r < 8; ++r) {
            float sum = red1[0][r] + red1[1][r] + red1[2][r] + red1[3][r];
            float ssq = red2[0][r] + red2[1][r] + red2[2][r] + red2[3][r];
            float mu = sum * (1.0f / 256.0f);
            float var = fmaxf(ssq * (1.0f / 256.0f) - mu * mu, 0.0f);
            float rstd = rsqrtf(var + 1e-5f);
            float t = (acc[r] - mu) * rstd * gg + bb;
            hb[r][j] = 0.5f * t * (1.0f + erff(t * 0.70710678118654752f));
        }
    }
    __syncthreads();

    // GEMM2: encoded[r][j2], j2 = tid&127, rows split by tid>>7; direct store
    const int j2 = tid & 127;
    const int rh = tid >> 7;
    float a2[4];
    {
        float bias2 = b2[j2];
        #pragma unroll
        for (int r = 0; r < 4; ++r) a2[r] = bias2;
    }
    for (int k = 0; k < 256; k += 4) {
        float w0 = W2[(k + 0) * 128 + j2];
        float w1 = W2[(k + 1) * 128 + j2];
        float w2v = W2[(k + 2) * 128 + j2];
        float w3 = W2[(k + 3) * 128 + j2];
        #pragma unroll
        for (int r = 0; r < 4; ++r) {
            float4 h = *((const float4*)&hb[rh * 4 + r][k]);
            a2[r] = fmaf(h.x, w0, a2[r]);
            a2[r] = fmaf(h.y, w1, a2[r]);
            a2[r] = fmaf(h.z, w2v, a2[r]);
            a2[r] = fmaf(h.w, w3, a2[r]);
        }
    }
    #pragma unroll
    for (int r = 0; r < 4; ++r)
        encoded[(rbase + rh * 4 + r) * 128 + j2] = a2[r];
}

// ---------------------------------------------------------------------------
// cnorm[k] = ||codebook[k]||^2  (one wave per codebook row)
// ---------------------------------------------------------------------------
__global__ __launch_bounds__(256) void cnorm_kernel(
    const float* __restrict__ cb, float* __restrict__ cnorm)
{
    const int tid = threadIdx.x;
    const int wave = tid >> 6, lane = tid & 63;
    const int row = blockIdx.x * 4 + wave;
    const float2 p = *((const float2*)(cb + row * 128 + lane * 2));
    float s = fmaf(p.x, p.x, p.y * p.y);
    #pragma unroll
    for (int m = 1; m < 64; m <<= 1) s += __shfl_xor(s, m, 64);
    if (lane == 0) cnorm[row] = s;
}

// ---------------------------------------------------------------------------
// Distance + argmin v2: LDS-instruction-bound fix.
// Block tile = 128 rows x 256 cols, K pre-split 4-way (grid = 128 x 4).
// Micro-tile 8x16 per thread (6 ds_read_b128 per 256 VALU-cyc vs 3 per 64
// before = 2.7x less LDS pipe pressure). score = ||c||^2 - 2 x.c (monotone
// with the reference distance). Strided col groups (tx*4 + g*64) keep b-reads
// at <=2-way banking; xs/cs padded (132/260) so staged b128 writes and all
// reads are conflict-balanced. Staging = 4x4 in-register transpose with
// ds_write_b128 (no scalar scatter).
// LDS: xs[32][132] 16.5KB + cs[32][260] 32.5KB = 49KB -> 2 blocks/CU,
// 8 waves/CU. First-index tie-break preserved (ascending scan + idx compare).
// ---------------------------------------------------------------------------
__global__ __launch_bounds__(256, 2) void dist_kernel(
    const float* __restrict__ encoded, const float* __restrict__ cb,
    const float* __restrict__ cnorm,
    float* __restrict__ part_min, int* __restrict__ part_idx)
{
    __shared__ float xs[32][132];   // [z][row]  16.5 KB (pad: banks spread)
    __shared__ float cs[32][260];   // [z][col]  32.5 KB (pad: banks spread)
    const int tid = threadIdx.x;
    const int tx = tid & 15;        // col group: cols tx*4 + g*64, g=0..3
    const int ty = tid >> 4;        // row group: rows ty*8 .. ty*8+7
    const int rtile = blockIdx.x & 127;
    const int kq = blockIdx.x >> 7; // K quarter (4096 cols each)
    const int rbase = rtile * 128;
    const int kbase = kq * 4096;

    float mv[8]; int mi[8];
    #pragma unroll
    for (int r = 0; r < 8; ++r) { mv[r] = 3.4e38f; mi[r] = 0; }

    // staging assignments (fixed per thread)
    const int xrq = (tid & 31) * 4;      // xs: row quad
    const int xzg = (tid >> 5) * 4;      // xs: z group
    const int ccq = (tid >> 3) * 4;      // cs: col quad (128 cols per pass)
    const int czg = (tid & 7) * 4;       // cs: z group

    for (int kc = 0; kc < 4096; kc += 256) {
        float acc[8][16];
        #pragma unroll
        for (int r = 0; r < 8; ++r)
            #pragma unroll
            for (int c = 0; c < 16; ++c) acc[r][c] = 0.0f;

        for (int zq = 0; zq < 4; ++zq) {
            __syncthreads();
            {   // stage xs[z][row]: 4x4 register transpose, b128 writes
                const float* src = encoded + (rbase + xrq) * 128 + zq * 32 + xzg;
                float4 v0 = *((const float4*)(src));
                float4 v1 = *((const float4*)(src + 128));
                float4 v2 = *((const float4*)(src + 256));
                float4 v3 = *((const float4*)(src + 384));
                *((float4*)&xs[xzg + 0][xrq]) = make_float4(v0.x, v1.x, v2.x, v3.x);
                *((float4*)&xs[xzg + 1][xrq]) = make_float4(v0.y, v1.y, v2.y, v3.y);
                *((float4*)&xs[xzg + 2][xrq]) = make_float4(v0.z, v1.z, v2.z, v3.z);
                *((float4*)&xs[xzg + 3][xrq]) = make_float4(v0.w, v1.w, v2.w, v3.w);
            }
            #pragma unroll
            for (int p = 0; p < 2; ++p) {  // stage cs[z][col]: 2 x 128 cols
                const int c0 = p * 128 + ccq;
                const float* src = cb + (kbase + kc + c0) * 128 + zq * 32 + czg;
                float4 v0 = *((const float4*)(src));
                float4 v1 = *((const float4*)(src + 128));
                float4 v2 = *((const float4*)(src + 256));
                float4 v3 = *((const float4*)(src + 384));
                *((float4*)&cs[czg + 0][c0]) = make_float4(v0.x, v1.x, v2.x, v3.x);
                *((float4*)&cs[czg + 1][c0]) = make_float4(v0.y, v1.y, v2.y, v3.y);
                *((float4*)&cs[czg + 2][c0]) = make_float4(v0.z, v1.z, v2.z, v3.z);
                *((float4*)&cs[czg + 3][c0]) = make_float4(v0.w, v1.w, v2.w, v3.w);
            }
            __syncthreads();

            #pragma unroll 2
            for (int z = 0; z < 32; ++z) {
                float4 a0 = *((const float4*)&xs[z][ty * 8]);
                float4 a1 = *((const float4*)&xs[z][ty * 8 + 4]);
                float4 b0 = *((const float4*)&cs[z][tx * 4]);
                float4 b1 = *((const float4*)&cs[z][tx * 4 + 64]);
                float4 b2 = *((const float4*)&cs[z][tx * 4 + 128]);
                float4 b3 = *((const float4*)&cs[z][tx * 4 + 192]);
                float av[8] = {a0.x, a0.y, a0.z, a0.w, a1.x, a1.y, a1.z, a1.w};
                float bv[16] = {b0.x, b0.y, b0.z, b0.w, b1.x, b1.y, b1.z, b1.w,
                                b2.x, b2.y, b2.z, b2.w, b3.x, b3.y, b3.z, b3.w};
                #pragma unroll
                for (int r = 0; r < 8; ++r)
                    #pragma unroll
                    for (int c = 0; c < 16; ++c)
                        acc[r][c] = fmaf(av[r], bv[c], acc[r][c]);
            }
        }

        // epilogue: ascending global index scan -> strict < keeps first min
        #pragma unroll
        for (int g = 0; g < 4; ++g) {
            #pragma unroll
            for (int jj = 0; jj < 4; ++jj) {
                const int cl = kc + g * 64 + tx * 4 + jj;   // local col in [0,4096)
                const float cn = cnorm[kbase + cl];
                #pragma unroll
                for (int r = 0; r < 8; ++r) {
                    float v = fmaf(-2.0f, acc[r][g * 4 + jj], cn);
                    if (v < mv[r]) { mv[r] = v; mi[r] = cl; }
                }
            }
        }
    }

    // cross-thread (16 col groups) reduce per row, idx tie-break
    __syncthreads();
    float* rv = (float*)&cs[0][0];        // 128*16 fp32 = 8KB
    int*   ri = (int*)(rv + 2048);        // next 8KB (fits in cs: 32.5KB)
    #pragma unroll
    for (int r = 0; r < 8; ++r) {
        rv[(ty * 8 + r) * 16 + tx] = mv[r];
        ri[(ty * 8 + r) * 16 + tx] = mi[r];
    }
    __syncthreads();
    if (tid < 128) {
        float bv = rv[tid * 16]; int bi = ri[tid * 16];
        #pragma unroll
        for (int t = 1; t < 16; ++t) {
            float v = rv[tid * 16 + t]; int ii = ri[tid * 16 + t];
            if (v < bv || (v == bv && ii < bi)) { bv = v; bi = ii; }
        }
        part_min[kq * 16384 + rbase + tid] = bv;
        part_idx[kq * 16384 + rbase + tid] = kbase + bi;
    }
}

// ---------------------------------------------------------------------------
// Decoder: combine the 4 K-quarter partials, gather codebook row, Linear->LN->
// GELU->Linear, per-row reconstruction MSE + global sum (for `scale`).
// ---------------------------------------------------------------------------
__global__ __launch_bounds__(256) void dec_kernel(
    const float* __restrict__ feat, const float* __restrict__ cb,
    const float* __restrict__ W3, const float* __restrict__ b3,
    const float* __restrict__ g2, const float* __restrict__ be2,
    const float* __restrict__ W4, const float* __restrict__ b4,
    const float* __restrict__ part_min, const int* __restrict__ part_idx,
    float* __restrict__ re_ws, float* __restrict__ sum_ws, int* __restrict__ idx_ws)
{
    __shared__ float qb[8][128];
    __shared__ float dh[8][256];
    __shared__ float red1[4][8];
    __shared__ float red2[4][8];
    __shared__ int idxs[8];
    const int tid = threadIdx.x;
    const int rbase = blockIdx.x * 8;

    if (tid < 8) {
        int b = rbase + tid;
        float bm = part_min[b]; int bi = part_idx[b];
        #pragma unroll
        for (int q = 1; q < 4; ++q) {
            float m = part_min[q * 16384 + b];
            int  ii = part_idx[q * 16384 + b];
            if (m < bm) { bm = m; bi = ii; }   // tie -> earlier quarter = smaller idx
        }
        int sel = min(max(bi, 0), KN - 1);     // never read OOB even on bad inputs
        idxs[tid] = sel;
        idx_ws[b] = sel;
    }
    __syncthreads();
    {
        int r = tid >> 5, i = (tid & 31) * 4;
        *((float4*)&qb[r][i]) = *((const float4*)(cb + idxs[r] * 128 + i));
    }
    __syncthreads();

    // GEMM3: t3[r][j], j = tid
    const int j = tid;
    float acc[8];
    {
        float bias = b3[j];
        #pragma unroll
        for (int r = 0; r < 8; ++r) acc[r] = bias;
    }
    for (int k = 0; k < 128; k += 4) {
        float w0 = W3[(k + 0) * 256 + j];
        float w1 = W3[(k + 1) * 256 + j];
        float w2 = W3[(k + 2) * 256 + j];
        float w3v = W3[(k + 3) * 256 + j];
        #pragma unroll
        for (int r = 0; r < 8; ++r) {
            float4 q = *((const float4*)&qb[r][k]);
            acc[r] = fmaf(q.x, w0, acc[r]);
            acc[r] = fmaf(q.y, w1, acc[r]);
            acc[r] = fmaf(q.z, w2, acc[r]);
            acc[r] = fmaf(q.w, w3v, acc[r]);
        }
    }

    // LayerNorm + GELU
    float s1[8], s2[8];
    #pragma unroll
    for (int r = 0; r < 8; ++r) { s1[r] = acc[r]; s2[r] = acc[r] * acc[r]; }
    #pragma unroll
    for (int m = 1; m < 64; m <<= 1) {
        #pragma unroll
        for (int r = 0; r < 8; ++r) {
            s1[r] += __shfl_xor(s1[r], m, 64);
            s2[r] += __shfl_xor(s2[r], m, 64);
        }
    }
    const int wave = tid >> 6, lane = tid & 63;
    if (lane == 0) {
        #pragma unroll
        for (int r = 0; r < 8; ++r) { red1[wave][r] = s1[r]; red2[wave][r] = s2[r]; }
    }
    __syncthreads();
    {
        float gg = g2[j], bb = be2[j];
        #pragma unroll
        for (int r = 0; r < 8; ++r) {
            float sum = red1[0][r] + red1[1][r] + red1[2][r] + red1[3][r];
            float ssq = red2[0][r] + red2[1][r] + red2[2][r] + red2[3][r];
            float mu = sum * (1.0f / 256.0f);
            float var = fmaxf(ssq * (1.0f / 256.0f) - mu * mu, 0.0f);
            float rstd = rsqrtf(var + 1e-5f);
            float t = (acc[r] - mu) * rstd * gg + bb;
            dh[r][j] = 0.5f * t * (1.0f + erff(t * 0.70710678118654752f));
        }
    }
    __syncthreads();

    // GEMM4: rec[r][d] for d = tid and tid+256, then squared error vs features
    float a0[8], a1[8];
    {
        float bias0 = b4[tid], bias1 = b4[tid + 256];
        #pragma unroll
        for (int r = 0; r < 8; ++r) { a0[r] = bias0; a1[r] = bias1; }
    }
    for (int k = 0; k < 256; k += 4) {
        float w00 = W4[(k + 0) * 512 + tid];
        float w01 = W4[(k + 0) * 512 + tid + 256];
        float w10 = W4[(k + 1) * 512 + tid];
        float w11 = W4[(k + 1) * 512 + tid + 256];
        float w20 = W4[(k + 2) * 512 + tid];
        float w21 = W4[(k + 2) * 512 + tid + 256];
        float w30 = W4[(k + 3) * 512 + tid];
        float w31 = W4[(k + 3) * 512 + tid + 256];
        #pragma unroll
        for (int r = 0; r < 8; ++r) {
            float4 h = *((const float4*)&dh[r][k]);
            a0[r] = fmaf(h.x, w00, a0[r]); a1[r] = fmaf(h.x, w01, a1[r]);
            a0[r] = fmaf(h.y, w10, a0[r]); a1[r] = fmaf(h.y, w11, a1[r]);
            a0[r] = fmaf(h.z, w20, a0[r]); a1[r] = fmaf(h.z, w21, a1[r]);
            a0[r] = fmaf(h.w, w30, a0[r]); a1[r] = fmaf(h.w, w31, a1[r]);
        }
    }
    float e[8];
    #pragma unroll
    for (int r = 0; r < 8; ++r) {
        float f0 = feat[(rbase + r) * 512 + tid];
        float f1 = feat[(rbase + r) * 512 + tid + 256];
        float d0 = a0[r] - f0, d1 = a1[r] - f1;
        e[r] = d0 * d0 + d1 * d1;
    }
    #pragma unroll
    for (int m = 1; m < 64; m <<= 1) {
        #pragma unroll
        for (int r = 0; r < 8; ++r) e[r] += __shfl_xor(e[r], m, 64);
    }
    if (lane == 0) {
        #pragma unroll
        for (int r = 0; r < 8; ++r) red1[wave][r] = e[r];
    }
    __syncthreads();
    if (tid < 8) {
        float s = (red1[0][tid] + red1[1][tid] + red1[2][tid] + red1[3][tid]) * (1.0f / 512.0f);
        re_ws[rbase + tid] = s;
        atomicAdd(sum_ws, s);
    }
}

// ---------------------------------------------------------------------------
// Finalize: scale = mean(re)+1e-8; MDL bits; write all 4 fp32 outputs.
// ---------------------------------------------------------------------------
__global__ __launch_bounds__(256) void fin_kernel(
    const float* __restrict__ re_ws, const float* __restrict__ sum_ws,
    const int* __restrict__ idx_ws, float* __restrict__ out)
{
    const int i = blockIdx.x * 256 + threadIdx.x;
    const float scale = (*sum_ws) * (1.0f / 16384.0f) + 1e-8f;
    const float re = re_ws[i];
    const float lp = -fabsf(re) / scale - logf(2.0f * scale);
    const float eb = -lp * 1.4426950408889634f;   // -log_prob / ln(2)
    const float tb = 14.0f + eb;                  // log2(K)=14
    const float ratio = 16384.0f / tb;            // D*32 = 16384
    out[i]             = re;
    out[16384 + i]     = ratio;
    out[2 * 16384 + i] = tb;
    out[3 * 16384 + i] = (float)idx_ws[i];
}

// ---------------------------------------------------------------------------
extern "C" void kernel_launch(void* const* d_in, const int* in_sizes, int n_in,
                              void* d_out, int out_size, void* d_ws, size_t ws_size,
                              hipStream_t stream)
{
    const float* feat = (const float*)d_in[0];
    const float* W1   = (const float*)d_in[1];
    const float* b1   = (const float*)d_in[2];
    const float* g1   = (const float*)d_in[3];
    const float* be1  = (const float*)d_in[4];
    const float* W2   = (const float*)d_in[5];
    const float* b2   = (const float*)d_in[6];
    const float* cb   = (const float*)d_in[7];
    const float* W3   = (const float*)d_in[8];
    const float* b3   = (const float*)d_in[9];
    const float* g2   = (const float*)d_in[10];
    const float* be2  = (const float*)d_in[11];
    const float* W4   = (const float*)d_in[12];
    const float* b4   = (const float*)d_in[13];

    char* ws = (char*)d_ws;
    float* encoded  = (float*)ws;                                        // 8 MB
    float* cnorm    = (float*)(ws + (size_t)(8u << 20));                 // 64 KB
    float* part_min = (float*)(ws + (size_t)(8u << 20) + (64u << 10));   // 256 KB (4 quarters)
    int*   part_idx = (int*)(ws + (size_t)(8u << 20) + (320u << 10));    // 256 KB
    float* re_ws    = (float*)(ws + (size_t)(8u << 20) + (576u << 10));  // 64 KB
    int*   idx_ws   = (int*)(ws + (size_t)(8u << 20) + (640u << 10));    // 64 KB
    float* sum_ws   = (float*)(ws + (size_t)(8u << 20) + (704u << 10));  // 4 B

    hipMemsetAsync(sum_ws, 0, sizeof(float), stream);

    hipLaunchKernelGGL(enc_kernel,  dim3(BN / 8), dim3(256), 0, stream,
                       feat, W1, b1, g1, be1, W2, b2, encoded);
    hipLaunchKernelGGL(cnorm_kernel, dim3(KN / 4), dim3(256), 0, stream, cb, cnorm);
    // grid = 128 row-tiles x 4 K-quarters; every part_min/part_idx entry is
    // written (no memset needed). Consecutive bids share a K-quarter ->
    // round-robin XCD dispatch keeps each XCD's 2MB codebook slice L2-hot.
    hipLaunchKernelGGL(dist_kernel, dim3((BN / 128) * 4), dim3(256), 0, stream,
                       encoded, cb, cnorm, part_min, part_idx);
    hipLaunchKernelGGL(dec_kernel,  dim3(BN / 8), dim3(256), 0, stream,
                       feat, cb, W3, b3, g2, be2, W4, b4,
                       part_min, part_idx, re_ws, sum_ws, idx_ws);
    hipLaunchKernelGGL(fin_kernel,  dim3(BN / 256), dim3(256), 0, stream,
                       re_ws, sum_ws, idx_ws, (float*)d_out);
}

// Round 2
// 867.731 us; speedup vs baseline: 1.3760x; 1.3760x over previous
//
#include <hip/hip_runtime.h>
#include <math.h>

// Problem constants (fixed by the reference)
#define BN 16384
#define DN 512
#define KN 16384
#define HN 256
#define ZN 128

typedef _Float16 f16x8 __attribute__((ext_vector_type(8)));
typedef _Float16 f16x4 __attribute__((ext_vector_type(4)));
typedef float f32x4 __attribute__((ext_vector_type(4)));

// ---------------------------------------------------------------------------
// Encoder: features[B,512] -> Linear(512,256) -> LN -> GELU -> Linear(256,128)
// writes encoded[B][128] fp32 AND its f16 hi/lo split (for the MFMA pass).
// Block = 256 threads, 8 rows per block.
// ---------------------------------------------------------------------------
__global__ __launch_bounds__(256) void enc_kernel(
    const float* __restrict__ feat, const float* __restrict__ W1, const float* __restrict__ b1,
    const float* __restrict__ g1, const float* __restrict__ be1,
    const float* __restrict__ W2, const float* __restrict__ b2,
    float* __restrict__ encoded, _Float16* __restrict__ xh, _Float16* __restrict__ xl)
{
    __shared__ float xf[8][512];
    __shared__ float hb[8][256];
    __shared__ float red1[4][8];
    __shared__ float red2[4][8];
    const int tid = threadIdx.x;
    const int rbase = blockIdx.x * 8;

    {
        const float4* src = (const float4*)(feat + rbase * 512);
        float4* dst = (float4*)&xf[0][0];
        #pragma unroll
        for (int i = 0; i < 4; ++i) dst[tid * 4 + i] = src[tid * 4 + i];
    }
    __syncthreads();

    // GEMM1: t1[r][j], j = tid (H=256 columns)
    const int j = tid;
    float acc[8];
    {
        float bias = b1[j];
        #pragma unroll
        for (int r = 0; r < 8; ++r) acc[r] = bias;
    }
    for (int k = 0; k < 512; k += 4) {
        float w0 = W1[(k + 0) * 256 + j];
        float w1 = W1[(k + 1) * 256 + j];
        float w2 = W1[(k + 2) * 256 + j];
        float w3 = W1[(k + 3) * 256 + j];
        #pragma unroll
        for (int r = 0; r < 8; ++r) {
            float4 x = *((const float4*)&xf[r][k]);
            acc[r] = fmaf(x.x, w0, acc[r]);
            acc[r] = fmaf(x.y, w1, acc[r]);
            acc[r] = fmaf(x.z, w2, acc[r]);
            acc[r] = fmaf(x.w, w3, acc[r]);
        }
    }

    // LayerNorm over H=256 (block-wide reduction), then exact GELU
    float s1[8], s2[8];
    #pragma unroll
    for (int r = 0; r < 8; ++r) { s1[r] = acc[r]; s2[r] = acc[r] * acc[r]; }
    #pragma unroll
    for (int m = 1; m < 64; m <<= 1) {
        #pragma unroll
        for (int r = 0; r < 8; ++r) {
            s1[r] += __shfl_xor(s1[r], m, 64);
            s2[r] += __shfl_xor(s2[r], m, 64);
        }
    }
    const int wave = tid >> 6, lane = tid & 63;
    if (lane == 0) {
        #pragma unroll
        for (int r = 0; r < 8; ++r) { red1[wave][r] = s1[r]; red2[wave][r] = s2[r]; }
    }
    __syncthreads();
    {
        float gg = g1[j], bb = be1[j];
        #pragma unroll
        for (int r = 0; r < 8; ++r) {
            float sum = red1[0][r] + red1[1][r] + red1[2][r] + red1[3][r];
            float ssq = red2[0][r] + red2[1][r] + red2[2][r] + red2[3][r];
            float mu = sum * (1.0f / 256.0f);
            float var = fmaxf(ssq * (1.0f / 256.0f) - mu * mu, 0.0f);
            float rstd = rsqrtf(var + 1e-5f);
            float t = (acc[r] - mu) * rstd * gg + bb;
            hb[r][j] = 0.5f * t * (1.0f + erff(t * 0.70710678118654752f));
        }
    }
    __syncthreads();

    // GEMM2: encoded[r][j2], j2 = tid&127, rows split by tid>>7
    const int j2 = tid & 127;
    const int rh = tid >> 7;
    float a2[4];
    {
        float bias2 = b2[j2];
        #pragma unroll
        for (int r = 0; r < 4; ++r) a2[r] = bias2;
    }
    for (int k = 0; k < 256; k += 4) {
        float w0 = W2[(k + 0) * 128 + j2];
        float w1 = W2[(k + 1) * 128 + j2];
        float w2v = W2[(k + 2) * 128 + j2];
        float w3 = W2[(k + 3) * 128 + j2];
        #pragma unroll
        for (int r = 0; r < 4; ++r) {
            float4 h = *((const float4*)&hb[rh * 4 + r][k]);
            a2[r] = fmaf(h.x, w0, a2[r]);
            a2[r] = fmaf(h.y, w1, a2[r]);
            a2[r] = fmaf(h.z, w2v, a2[r]);
            a2[r] = fmaf(h.w, w3, a2[r]);
        }
    }
    #pragma unroll
    for (int r = 0; r < 4; ++r) {
        const int idx = (rbase + rh * 4 + r) * 128 + j2;
        const float v = a2[r];
        encoded[idx] = v;
        _Float16 hh = (_Float16)v;
        xh[idx] = hh;
        xl[idx] = (_Float16)(v - (float)hh);
    }
}

// ---------------------------------------------------------------------------
// cnorm[k] = ||codebook[k]||^2  (one wave per codebook row)
// ---------------------------------------------------------------------------
__global__ __launch_bounds__(256) void cnorm_kernel(
    const float* __restrict__ cb, float* __restrict__ cnorm)
{
    const int tid = threadIdx.x;
    const int wave = tid >> 6, lane = tid & 63;
    const int row = blockIdx.x * 4 + wave;
    const float2 p = *((const float2*)(cb + row * 128 + lane * 2));
    float s = fmaf(p.x, p.x, p.y * p.y);
    #pragma unroll
    for (int m = 1; m < 64; m <<= 1) s += __shfl_xor(s, m, 64);
    if (lane == 0) cnorm[row] = s;
}

// ---------------------------------------------------------------------------
// Split codebook into f16 hi/lo: ch = f16(c), cl = f16(c - ch).
// Grid 2048 blocks x 256 threads, 8 rows (1024 elems) per block.
// ---------------------------------------------------------------------------
__global__ __launch_bounds__(256) void split_kernel(
    const float* __restrict__ cb, _Float16* __restrict__ ch, _Float16* __restrict__ cl)
{
    const size_t base = (size_t)blockIdx.x * 1024 + threadIdx.x * 4;
    float4 v = *(const float4*)(cb + base);
    f16x4 h, l;
    h.x = (_Float16)v.x; l.x = (_Float16)(v.x - (float)h.x);
    h.y = (_Float16)v.y; l.y = (_Float16)(v.y - (float)h.y);
    h.z = (_Float16)v.z; l.z = (_Float16)(v.z - (float)h.z);
    h.w = (_Float16)v.w; l.w = (_Float16)(v.w - (float)h.w);
    *(f16x4*)(ch + base) = h;
    *(f16x4*)(cl + base) = l;
}

// ---------------------------------------------------------------------------
// Pass A: MFMA distance group-minima.
// score(b,k) = ||c_k||^2 - 2 x_b.c_k  (monotone with reference distance).
// Dot via split-f16, 3 MFMA terms: xh.ch + xh.cl + xl.ch accumulated fp32.
// |score_approx - score_exact| <= ~2e-3 worst case (f16-denorm pessimism).
// Block tile 64x64, K=128 staged once. 4 waves, wave tile 32x32 via
// mfma_f32_16x16x32_f16 (A: row=lane&15, k=(lane>>4)*8+j; B: col=lane&15,
// same k; C/D: col=lane&15, row=(lane>>4)*4+reg — verified m89/m91 family).
// LDS 64KB static, XOR chunk swizzle (c ^= row&7) -> all ds_read_b128 /
// ds_write_b128 land uniformly on 8 bank-quads = 8-cyc floor, no conflicts.
// Output: g_ws[ctile][row] = min over the tile's 64 cols (fp32).
// ---------------------------------------------------------------------------
__global__ __launch_bounds__(256, 2) void mfma_dist_kernel(
    const _Float16* __restrict__ xh, const _Float16* __restrict__ xl,
    const _Float16* __restrict__ ch, const _Float16* __restrict__ cl,
    const float* __restrict__ cnorm, float* __restrict__ g_ws)
{
    __shared__ _Float16 ash[64 * 128];
    __shared__ _Float16 asl[64 * 128];
    __shared__ _Float16 bsh[64 * 128];
    __shared__ _Float16 bsl[64 * 128];
    const int tid = threadIdx.x;
    const int bid = blockIdx.x;
    const int rtile = bid & 255, ctile = bid >> 8;   // row inner: per-XCD X slice stays L2-hot
    const int rbase = rtile * 64, cbase = ctile * 64;

    {   // stage 64KB: 4 arrays x 64 rows x 16 chunks(16B); thread: row=tid>>2, 4 chunks
        const int row = tid >> 2;
        #pragma unroll
        for (int i = 0; i < 4; ++i) {
            const int c = i * 4 + (tid & 3);                  // 4 lanes cover 64B contiguous
            const int lidx = row * 128 + ((c ^ (row & 7)) * 8);
            const size_t gx = (size_t)(rbase + row) * 128 + c * 8;
            const size_t gc = (size_t)(cbase + row) * 128 + c * 8;
            *(f16x8*)(ash + lidx) = *(const f16x8*)(xh + gx);
            *(f16x8*)(asl + lidx) = *(const f16x8*)(xl + gx);
            *(f16x8*)(bsh + lidx) = *(const f16x8*)(ch + gc);
            *(f16x8*)(bsl + lidx) = *(const f16x8*)(cl + gc);
        }
    }
    __syncthreads();

    const int wid = tid >> 6, l = tid & 63;
    const int wm = wid & 1, wn = wid >> 1;   // wave tile: rows wm*32, cols wn*32
    const int lr = l & 15, lg = l >> 4;

    f32x4 acc[2][2];
    #pragma unroll
    for (int mt = 0; mt < 2; ++mt)
        #pragma unroll
        for (int nt = 0; nt < 2; ++nt) {
            f32x4 z = {0.0f, 0.0f, 0.0f, 0.0f};
            acc[mt][nt] = z;
        }

    #pragma unroll
    for (int ks = 0; ks < 4; ++ks) {
        const int cc = ks * 4 + lg;          // 16B chunk index along K
        f16x8 aH[2], aL[2], bH[2], bL[2];
        #pragma unroll
        for (int mt = 0; mt < 2; ++mt) {
            const int row = wm * 32 + mt * 16 + lr;
            const int idx = row * 128 + ((cc ^ (row & 7)) * 8);
            aH[mt] = *(const f16x8*)(ash + idx);
            aL[mt] = *(const f16x8*)(asl + idx);
        }
        #pragma unroll
        for (int nt = 0; nt < 2; ++nt) {
            const int row = wn * 32 + nt * 16 + lr;
            const int idx = row * 128 + ((cc ^ (row & 7)) * 8);
            bH[nt] = *(const f16x8*)(bsh + idx);
            bL[nt] = *(const f16x8*)(bsl + idx);
        }
        #pragma unroll
        for (int mt = 0; mt < 2; ++mt)
            #pragma unroll
            for (int nt = 0; nt < 2; ++nt) {
                acc[mt][nt] = __builtin_amdgcn_mfma_f32_16x16x32_f16(aH[mt], bH[nt], acc[mt][nt], 0, 0, 0);
                acc[mt][nt] = __builtin_amdgcn_mfma_f32_16x16x32_f16(aH[mt], bL[nt], acc[mt][nt], 0, 0, 0);
                acc[mt][nt] = __builtin_amdgcn_mfma_f32_16x16x32_f16(aL[mt], bH[nt], acc[mt][nt], 0, 0, 0);
            }
    }

    // epilogue: per-thread min over its cols, then across the 16 lr lanes
    float cn[2];
    #pragma unroll
    for (int nt = 0; nt < 2; ++nt) cn[nt] = cnorm[cbase + wn * 32 + nt * 16 + lr];

    float pm[2][4];
    #pragma unroll
    for (int mt = 0; mt < 2; ++mt)
        #pragma unroll
        for (int r = 0; r < 4; ++r) {
            float v0 = fmaf(-2.0f, acc[mt][0][r], cn[0]);
            float v1 = fmaf(-2.0f, acc[mt][1][r], cn[1]);
            pm[mt][r] = fminf(v0, v1);
        }
    #pragma unroll
    for (int mask = 1; mask < 16; mask <<= 1)
        #pragma unroll
        for (int mt = 0; mt < 2; ++mt)
            #pragma unroll
            for (int r = 0; r < 4; ++r)
                pm[mt][r] = fminf(pm[mt][r], __shfl_xor(pm[mt][r], mask, 64));

    __syncthreads();                      // compute done; reuse LDS
    float* gpart = (float*)ash;           // [2 wn][64 rows]
    if (lr == 0) {
        #pragma unroll
        for (int mt = 0; mt < 2; ++mt)
            #pragma unroll
            for (int r = 0; r < 4; ++r)
                gpart[wn * 64 + wm * 32 + mt * 16 + lg * 4 + r] = pm[mt][r];
    }
    __syncthreads();
    if (tid < 64)
        g_ws[(size_t)ctile * 16384 + rbase + tid] = fminf(gpart[tid], gpart[64 + tid]);
}

// ---------------------------------------------------------------------------
// Pass B: exact fp32 refine. For each row: m = min over 256 group minima;
// any group with g <= m + EPS provably contains the exact argmin (and every
// exact tie), since EPS >= 2x the approx error. Re-scan those groups with
// exact fp32 dots; lexicographic (value, index) min = first-index tie-break.
// ---------------------------------------------------------------------------
#define REFINE_EPS 0.05f
__global__ __launch_bounds__(128) void refine_kernel(
    const float* __restrict__ encoded, const float* __restrict__ cb,
    const float* __restrict__ cnorm, const float* __restrict__ g_ws,
    int* __restrict__ idx_ws)
{
    __shared__ float gsm[256];
    __shared__ float xsm[128];
    __shared__ float mpart[2];
    __shared__ float wred[2];
    __shared__ int wredi[2];
    const int row = blockIdx.x;
    const int t = threadIdx.x;

    float g0 = g_ws[(size_t)t * 16384 + row];
    float g1 = g_ws[(size_t)(128 + t) * 16384 + row];
    gsm[t] = g0; gsm[128 + t] = g1;
    xsm[t] = encoded[(size_t)row * 128 + t];

    float m = fminf(g0, g1);
    #pragma unroll
    for (int mask = 1; mask < 64; mask <<= 1) m = fminf(m, __shfl_xor(m, mask, 64));
    if ((t & 63) == 0) mpart[t >> 6] = m;
    __syncthreads();
    const float thr = fminf(mpart[0], mpart[1]) + REFINE_EPS;

    float bv = 3.4e38f; int bi = 0;
    for (int grp = 0; grp < 256; ++grp) {        // ascending: keeps first index
        if (gsm[grp] <= thr) {
            if (t < 64) {
                const int col = grp * 64 + t;
                const float4* cp = (const float4*)(cb + (size_t)col * 128);
                float acc = 0.0f;
                #pragma unroll 8
                for (int z = 0; z < 32; ++z) {
                    float4 c4 = cp[z];
                    acc = fmaf(xsm[4 * z + 0], c4.x, acc);
                    acc = fmaf(xsm[4 * z + 1], c4.y, acc);
                    acc = fmaf(xsm[4 * z + 2], c4.z, acc);
                    acc = fmaf(xsm[4 * z + 3], c4.w, acc);
                }
                float v = fmaf(-2.0f, acc, cnorm[col]);
                if (v < bv) { bv = v; bi = col; }   // strict <: earliest col wins
            }
        }
    }
    #pragma unroll
    for (int mask = 1; mask < 64; mask <<= 1) {
        float ov = __shfl_xor(bv, mask, 64);
        int oi = __shfl_xor(bi, mask, 64);
        if (ov < bv || (ov == bv && oi < bi)) { bv = ov; bi = oi; }
    }
    if ((t & 63) == 0) { wred[t >> 6] = bv; wredi[t >> 6] = bi; }
    __syncthreads();
    if (t == 0) {
        float v1 = wred[1]; int i1 = wredi[1];
        if (v1 < bv || (v1 == bv && i1 < bi)) { bv = v1; bi = i1; }
        idx_ws[row] = min(max(bi, 0), KN - 1);
    }
}

// ---------------------------------------------------------------------------
// Decoder: gather codebook row by refined index, Linear->LN->GELU->Linear,
// per-row reconstruction MSE + global sum (for `scale`).
// ---------------------------------------------------------------------------
__global__ __launch_bounds__(256) void dec_kernel(
    const float* __restrict__ feat, const float* __restrict__ cb,
    const float* __restrict__ W3, const float* __restrict__ b3,
    const float* __restrict__ g2, const float* __restrict__ be2,
    const float* __restrict__ W4, const float* __restrict__ b4,
    const int* __restrict__ idx_ws,
    float* __restrict__ re_ws, float* __restrict__ sum_ws)
{
    __shared__ float qb[8][128];
    __shared__ float dh[8][256];
    __shared__ float red1[4][8];
    __shared__ float red2[4][8];
    __shared__ int idxs[8];
    const int tid = threadIdx.x;
    const int rbase = blockIdx.x * 8;

    if (tid < 8) idxs[tid] = idx_ws[rbase + tid];   // already clamped by refine
    __syncthreads();
    {
        int r = tid >> 5, i = (tid & 31) * 4;
        *((float4*)&qb[r][i]) = *((const float4*)(cb + idxs[r] * 128 + i));
    }
    __syncthreads();

    // GEMM3: t3[r][j], j = tid
    const int j = tid;
    float acc[8];
    {
        float bias = b3[j];
        #pragma unroll
        for (int r = 0; r < 8; ++r) acc[r] = bias;
    }
    for (int k = 0; k < 128; k += 4) {
        float w0 = W3[(k + 0) * 256 + j];
        float w1 = W3[(k + 1) * 256 + j];
        float w2 = W3[(k + 2) * 256 + j];
        float w3v = W3[(k + 3) * 256 + j];
        #pragma unroll
        for (int r = 0; r < 8; ++r) {
            float4 q = *((const float4*)&qb[r][k]);
            acc[r] = fmaf(q.x, w0, acc[r]);
            acc[r] = fmaf(q.y, w1, acc[r]);
            acc[r] = fmaf(q.z, w2, acc[r]);
            acc[r] = fmaf(q.w, w3v, acc[r]);
        }
    }

    // LayerNorm + GELU
    float s1[8], s2[8];
    #pragma unroll
    for (int r = 0; r < 8; ++r) { s1[r] = acc[r]; s2[r] = acc[r] * acc[r]; }
    #pragma unroll
    for (int m = 1; m < 64; m <<= 1) {
        #pragma unroll
        for (int r = 0; r < 8; ++r) {
            s1[r] += __shfl_xor(s1[r], m, 64);
            s2[r] += __shfl_xor(s2[r], m, 64);
        }
    }
    const int wave = tid >> 6, lane = tid & 63;
    if (lane == 0) {
        #pragma unroll
        for (int r = 0; r < 8; ++r) { red1[wave][r] = s1[r]; red2[wave][r] = s2[r]; }
    }
    __syncthreads();
    {
        float gg = g2[j], bb = be2[j];
        #pragma unroll
        for (int r = 0; r < 8; ++r) {
            float sum = red1[0][r] + red1[1][r] + red1[2][r] + red1[3][r];
            float ssq = red2[0][r] + red2[1][r] + red2[2][r] + red2[3][r];
            float mu = sum * (1.0f / 256.0f);
            float var = fmaxf(ssq * (1.0f / 256.0f) - mu * mu, 0.0f);
            float rstd = rsqrtf(var + 1e-5f);
            float t = (acc[r] - mu) * rstd * gg + bb;
            dh[r][j] = 0.5f * t * (1.0f + erff(t * 0.70710678118654752f));
        }
    }
    __syncthreads();

    // GEMM4: rec[r][d] for d = tid and tid+256, then squared error vs features
    float a0[8], a1[8];
    {
        float bias0 = b4[tid], bias1 = b4[tid + 256];
        #pragma unroll
        for (int r = 0; r < 8; ++r) { a0[r] = bias0; a1[r] = bias1; }
    }
    for (int k = 0; k < 256; k += 4) {
        float w00 = W4[(k + 0) * 512 + tid];
        float w01 = W4[(k + 0) * 512 + tid + 256];
        float w10 = W4[(k + 1) * 512 + tid];
        float w11 = W4[(k + 1) * 512 + tid + 256];
        float w20 = W4[(k + 2) * 512 + tid];
        float w21 = W4[(k + 2) * 512 + tid + 256];
        float w30 = W4[(k + 3) * 512 + tid];
        float w31 = W4[(k + 3) * 512 + tid + 256];
        #pragma unroll
        for (int r = 0; r < 8; ++r) {
            float4 h = *((const float4*)&dh[r][k]);
            a0[r] = fmaf(h.x, w00, a0[r]); a1[r] = fmaf(h.x, w01, a1[r]);
            a0[r] = fmaf(h.y, w10, a0[r]); a1[r] = fmaf(h.y, w11, a1[r]);
            a0[r] = fmaf(h.z, w20, a0[r]); a1[r] = fmaf(h.z, w21, a1[r]);
            a0[r] = fmaf(h.w, w30, a0[r]); a1[r] = fmaf(h.w, w31, a1[r]);
        }
    }
    float e[8];
    #pragma unroll
    for (int r = 0; r < 8; ++r) {
        float f0 = feat[(rbase + r) * 512 + tid];
        float f1 = feat[(rbase + r) * 512 + tid + 256];
        float d0 = a0[r] - f0, d1 = a1[r] - f1;
        e[r] = d0 * d0 + d1 * d1;
    }
    #pragma unroll
    for (int m = 1; m < 64; m <<= 1) {
        #pragma unroll
        for (int r = 0; r < 8; ++r) e[r] += __shfl_xor(e[r], m, 64);
    }
    if (lane == 0) {
        #pragma unroll
        for (int r = 0; r < 8; ++r) red1[wave][r] = e[r];
    }
    __syncthreads();
    if (tid < 8) {
        float s = (red1[0][tid] + red1[1][tid] + red1[2][tid] + red1[3][tid]) * (1.0f / 512.0f);
        re_ws[rbase + tid] = s;
        atomicAdd(sum_ws, s);
    }
}

// ---------------------------------------------------------------------------
// Finalize: scale = mean(re)+1e-8; MDL bits; write all 4 fp32 outputs.
// ---------------------------------------------------------------------------
__global__ __launch_bounds__(256) void fin_kernel(
    const float* __restrict__ re_ws, const float* __restrict__ sum_ws,
    const int* __restrict__ idx_ws, float* __restrict__ out)
{
    const int i = blockIdx.x * 256 + threadIdx.x;
    const float scale = (*sum_ws) * (1.0f / 16384.0f) + 1e-8f;
    const float re = re_ws[i];
    const float lp = -fabsf(re) / scale - logf(2.0f * scale);
    const float eb = -lp * 1.4426950408889634f;   // -log_prob / ln(2)
    const float tb = 14.0f + eb;                  // log2(K)=14
    const float ratio = 16384.0f / tb;            // D*32 = 16384
    out[i]             = re;
    out[16384 + i]     = ratio;
    out[2 * 16384 + i] = tb;
    out[3 * 16384 + i] = (float)idx_ws[i];
}

// ---------------------------------------------------------------------------
extern "C" void kernel_launch(void* const* d_in, const int* in_sizes, int n_in,
                              void* d_out, int out_size, void* d_ws, size_t ws_size,
                              hipStream_t stream)
{
    const float* feat = (const float*)d_in[0];
    const float* W1   = (const float*)d_in[1];
    const float* b1   = (const float*)d_in[2];
    const float* g1   = (const float*)d_in[3];
    const float* be1  = (const float*)d_in[4];
    const float* W2   = (const float*)d_in[5];
    const float* b2   = (const float*)d_in[6];
    const float* cb   = (const float*)d_in[7];
    const float* W3   = (const float*)d_in[8];
    const float* b3   = (const float*)d_in[9];
    const float* g2   = (const float*)d_in[10];
    const float* be2  = (const float*)d_in[11];
    const float* W4   = (const float*)d_in[12];
    const float* b4   = (const float*)d_in[13];

    char* ws = (char*)d_ws;
    const size_t MB = 1u << 20;
    float*    encoded = (float*)ws;                          // 8 MB
    _Float16* xh      = (_Float16*)(ws + 8 * MB);            // 4 MB
    _Float16* xl      = (_Float16*)(ws + 12 * MB);           // 4 MB
    _Float16* chh     = (_Float16*)(ws + 16 * MB);           // 4 MB
    _Float16* cll     = (_Float16*)(ws + 20 * MB);           // 4 MB
    float*    g_ws    = (float*)(ws + 24 * MB);              // 16 MB [256][16384]
    float*    cnorm   = (float*)(ws + 40 * MB);              // 64 KB
    float*    re_ws   = (float*)(ws + 40 * MB + (64u << 10));// 64 KB
    int*      idx_ws  = (int*)(ws + 40 * MB + (128u << 10)); // 64 KB
    float*    sum_ws  = (float*)(ws + 40 * MB + (192u << 10));// 4 B

    hipMemsetAsync(sum_ws, 0, sizeof(float), stream);

    hipLaunchKernelGGL(enc_kernel,  dim3(BN / 8), dim3(256), 0, stream,
                       feat, W1, b1, g1, be1, W2, b2, encoded, xh, xl);
    hipLaunchKernelGGL(split_kernel, dim3(KN / 8), dim3(256), 0, stream, cb, chh, cll);
    hipLaunchKernelGGL(cnorm_kernel, dim3(KN / 4), dim3(256), 0, stream, cb, cnorm);
    // grid = 256 row-tiles (inner) x 256 col-tiles: per-XCD X slice (1MB) and
    // current codebook tile stay L2-resident.
    hipLaunchKernelGGL(mfma_dist_kernel, dim3(256 * 256), dim3(256), 0, stream,
                       xh, xl, chh, cll, cnorm, g_ws);
    hipLaunchKernelGGL(refine_kernel, dim3(BN), dim3(128), 0, stream,
                       encoded, cb, cnorm, g_ws, idx_ws);
    hipLaunchKernelGGL(dec_kernel,  dim3(BN / 8), dim3(256), 0, stream,
                       feat, cb, W3, b3, g2, be2, W4, b4,
                       idx_ws, re_ws, sum_ws);
    hipLaunchKernelGGL(fin_kernel,  dim3(BN / 256), dim3(256), 0, stream,
                       re_ws, sum_ws, idx_ws, (float*)d_out);
}

// Round 3
// 643.966 us; speedup vs baseline: 1.8542x; 1.3475x over previous
//
#include <hip/hip_runtime.h>
#include <math.h>

// Problem constants (fixed by the reference)
#define BN 16384
#define DN 512
#define KN 16384
#define HN 256
#define ZN 128

typedef _Float16 f16x8 __attribute__((ext_vector_type(8)));
typedef _Float16 f16x4 __attribute__((ext_vector_type(4)));
typedef float f32x4 __attribute__((ext_vector_type(4)));

// ---------------------------------------------------------------------------
// Encoder: features[B,512] -> Linear(512,256) -> LN -> GELU -> Linear(256,128)
// writes encoded[B][128] fp32 AND its f16 hi/lo split (row-major, read as
// A-fragments directly by mfma_dist). Block = 256 threads, 8 rows per block.
// ---------------------------------------------------------------------------
__global__ __launch_bounds__(256) void enc_kernel(
    const float* __restrict__ feat, const float* __restrict__ W1, const float* __restrict__ b1,
    const float* __restrict__ g1, const float* __restrict__ be1,
    const float* __restrict__ W2, const float* __restrict__ b2,
    float* __restrict__ encoded, _Float16* __restrict__ xh, _Float16* __restrict__ xl)
{
    __shared__ float xf[8][512];
    __shared__ float hb[8][256];
    __shared__ float red1[4][8];
    __shared__ float red2[4][8];
    const int tid = threadIdx.x;
    const int rbase = blockIdx.x * 8;

    {
        const float4* src = (const float4*)(feat + rbase * 512);
        float4* dst = (float4*)&xf[0][0];
        #pragma unroll
        for (int i = 0; i < 4; ++i) dst[tid * 4 + i] = src[tid * 4 + i];
    }
    __syncthreads();

    // GEMM1: t1[r][j], j = tid (H=256 columns)
    const int j = tid;
    float acc[8];
    {
        float bias = b1[j];
        #pragma unroll
        for (int r = 0; r < 8; ++r) acc[r] = bias;
    }
    for (int k = 0; k < 512; k += 4) {
        float w0 = W1[(k + 0) * 256 + j];
        float w1 = W1[(k + 1) * 256 + j];
        float w2 = W1[(k + 2) * 256 + j];
        float w3 = W1[(k + 3) * 256 + j];
        #pragma unroll
        for (int r = 0; r < 8; ++r) {
            float4 x = *((const float4*)&xf[r][k]);
            acc[r] = fmaf(x.x, w0, acc[r]);
            acc[r] = fmaf(x.y, w1, acc[r]);
            acc[r] = fmaf(x.z, w2, acc[r]);
            acc[r] = fmaf(x.w, w3, acc[r]);
        }
    }

    // LayerNorm over H=256 (block-wide reduction), then exact GELU
    float s1[8], s2[8];
    #pragma unroll
    for (int r = 0; r < 8; ++r) { s1[r] = acc[r]; s2[r] = acc[r] * acc[r]; }
    #pragma unroll
    for (int m = 1; m < 64; m <<= 1) {
        #pragma unroll
        for (int r = 0; r < 8; ++r) {
            s1[r] += __shfl_xor(s1[r], m, 64);
            s2[r] += __shfl_xor(s2[r], m, 64);
        }
    }
    const int wave = tid >> 6, lane = tid & 63;
    if (lane == 0) {
        #pragma unroll
        for (int r = 0; r < 8; ++r) { red1[wave][r] = s1[r]; red2[wave][r] = s2[r]; }
    }
    __syncthreads();
    {
        float gg = g1[j], bb = be1[j];
        #pragma unroll
        for (int r = 0; r < 8; ++r) {
            float sum = red1[0][r] + red1[1][r] + red1[2][r] + red1[3][r];
            float ssq = red2[0][r] + red2[1][r] + red2[2][r] + red2[3][r];
            float mu = sum * (1.0f / 256.0f);
            float var = fmaxf(ssq * (1.0f / 256.0f) - mu * mu, 0.0f);
            float rstd = rsqrtf(var + 1e-5f);
            float t = (acc[r] - mu) * rstd * gg + bb;
            hb[r][j] = 0.5f * t * (1.0f + erff(t * 0.70710678118654752f));
        }
    }
    __syncthreads();

    // GEMM2: encoded[r][j2], j2 = tid&127, rows split by tid>>7
    const int j2 = tid & 127;
    const int rh = tid >> 7;
    float a2[4];
    {
        float bias2 = b2[j2];
        #pragma unroll
        for (int r = 0; r < 4; ++r) a2[r] = bias2;
    }
    for (int k = 0; k < 256; k += 4) {
        float w0 = W2[(k + 0) * 128 + j2];
        float w1 = W2[(k + 1) * 128 + j2];
        float w2v = W2[(k + 2) * 128 + j2];
        float w3 = W2[(k + 3) * 128 + j2];
        #pragma unroll
        for (int r = 0; r < 4; ++r) {
            float4 h = *((const float4*)&hb[rh * 4 + r][k]);
            a2[r] = fmaf(h.x, w0, a2[r]);
            a2[r] = fmaf(h.y, w1, a2[r]);
            a2[r] = fmaf(h.z, w2v, a2[r]);
            a2[r] = fmaf(h.w, w3, a2[r]);
        }
    }
    #pragma unroll
    for (int r = 0; r < 4; ++r) {
        const int idx = (rbase + rh * 4 + r) * 128 + j2;
        const float v = a2[r];
        encoded[idx] = v;
        _Float16 hh = (_Float16)v;
        xh[idx] = hh;
        xl[idx] = (_Float16)(v - (float)hh);
    }
}

// ---------------------------------------------------------------------------
// Split+pack codebook into MFMA-fragment-linear blobs AND compute cnorm.
// Blob layout per ctile c (64 cols): 32KB = [hi/lo][nt(4)][q(16)][lr(16)][8]
// halves, so LDS staging is a straight linear copy (global_load_lds) and
// fragment ds_reads are 256B-contiguous per quarter-wave (conflict-free).
// Element (col,k): off = (col>>6)*16384 + hl*8192 + ((col>>4)&3)*2048
//                      + (k>>3)*128 + (col&15)*8 + (k&7).
// Block = 256 threads, 8 codebook rows; 32 threads per row.
// ---------------------------------------------------------------------------
__global__ __launch_bounds__(256) void split_kernel(
    const float* __restrict__ cb, _Float16* __restrict__ cpk, float* __restrict__ cnorm)
{
    const int t = threadIdx.x;
    const int col = blockIdx.x * 8 + (t >> 5);
    const int k0 = (t & 31) * 4;
    float4 v = *(const float4*)(cb + (size_t)col * 128 + k0);
    f16x4 h, l;
    h.x = (_Float16)v.x; l.x = (_Float16)(v.x - (float)h.x);
    h.y = (_Float16)v.y; l.y = (_Float16)(v.y - (float)h.y);
    h.z = (_Float16)v.z; l.z = (_Float16)(v.z - (float)h.z);
    h.w = (_Float16)v.w; l.w = (_Float16)(v.w - (float)h.w);
    const size_t base = (size_t)(col >> 6) * 16384 + (size_t)((col >> 4) & 3) * 2048
                      + (size_t)(k0 >> 3) * 128 + (size_t)(col & 15) * 8 + (k0 & 7);
    *(f16x4*)(cpk + base) = h;
    *(f16x4*)(cpk + base + 8192) = l;

    float s = v.x * v.x + v.y * v.y + v.z * v.z + v.w * v.w;
    #pragma unroll
    for (int m = 1; m < 32; m <<= 1) s += __shfl_xor(s, m, 64);
    if ((t & 31) == 0) cnorm[col] = s;
}

// ---------------------------------------------------------------------------
// Pass A: MFMA distance group-minima (persistent-A / streamed-B pipeline).
// score(b,k) = ||c_k||^2 - 2 x_b.c_k via 3-term split f16 MFMA (err ~1e-4).
// Block = 4 waves x 32 rows = 128 rows; grid = 128 row-blocks x 4 K-quarters
// = 512 = exactly 2 blocks/CU. bid&3 = quarter -> each XCD's 2MB B slice
// stays L2-resident. A hi/lo frags live in 64 VGPRs (loaded once, row-major).
// B: 64-col ctile blobs (32KB) streamed through double-buffered LDS via
// linear global_load_lds; counted s_waitcnt vmcnt(8) keeps the next blob in
// flight across raw s_barriers (prefetch never drained). Fragment ds_reads
// are contiguous per quarter-wave -> zero bank conflicts.
// Per ctile per wave: 8 global_load_lds + 32 ds_read_b128 + 96 MFMA.
// Output: g_ws[row][ctile] (row-major for coalesced refine reads).
// ---------------------------------------------------------------------------
__global__ __launch_bounds__(256, 2) void mfma_dist_kernel(
    const _Float16* __restrict__ xh, const _Float16* __restrict__ xl,
    const _Float16* __restrict__ cpk, const float* __restrict__ cnorm,
    float* __restrict__ g_ws)
{
    __shared__ __align__(16) _Float16 bs[2][16384];   // 2 x 32KB
    const int tid = threadIdx.x;
    const int w = tid >> 6, l = tid & 63;
    const int lr = l & 15, lg = l >> 4;
    const int q4 = blockIdx.x & 3;          // K-quarter (64 ctiles)
    const int r128 = blockIdx.x >> 2;       // row-block
    const int rbase = r128 * 128 + w * 32;  // this wave's 32 rows
    const int ctbase = q4 * 64;

    // A fragments in registers: [mt][ks], hi+lo (64 VGPRs)
    f16x8 aH[2][4], aL[2][4];
    #pragma unroll
    for (int mt = 0; mt < 2; ++mt) {
        const size_t rowoff = (size_t)(rbase + mt * 16 + lr) * 128;
        #pragma unroll
        for (int ks = 0; ks < 4; ++ks) {
            aH[mt][ks] = *(const f16x8*)(xh + rowoff + ks * 32 + lg * 8);
            aL[mt][ks] = *(const f16x8*)(xl + rowoff + ks * 32 + lg * 8);
        }
    }

    // linear async staging: wave w copies its 8KB of the 32KB blob
    const char* cpkb = (const char*)cpk;
    char* lds0 = (char*)&bs[0][0];
    auto stage = [&](int buf, int ct) {
        const char* src = cpkb + ((size_t)(ctbase + ct) << 15) + (w << 13) + l * 16;
        char* dst = lds0 + (buf << 15) + (w << 13);
        #pragma unroll
        for (int i = 0; i < 8; ++i) {
            __builtin_amdgcn_global_load_lds(
                (const __attribute__((address_space(1))) unsigned int*)(src + i * 1024),
                (__attribute__((address_space(3))) unsigned int*)(dst + i * 1024),
                16, 0, 0);
        }
    };

    stage(0, 0);

    int cur = 0;
    for (int t = 0; t < 64; ++t) {
        if (t < 63) {
            stage(cur ^ 1, t + 1);
            asm volatile("s_waitcnt vmcnt(8)" ::: "memory");  // drain cur, keep next in flight
        } else {
            asm volatile("s_waitcnt vmcnt(0)" ::: "memory");
        }
        __builtin_amdgcn_s_barrier();
        asm volatile("" ::: "memory");

        const _Float16* bb = &bs[cur][0];
        f32x4 acc[2][4];
        #pragma unroll
        for (int mt = 0; mt < 2; ++mt)
            #pragma unroll
            for (int nt = 0; nt < 4; ++nt) {
                f32x4 z = {0.0f, 0.0f, 0.0f, 0.0f};
                acc[mt][nt] = z;
            }

        #pragma unroll
        for (int ks = 0; ks < 4; ++ks) {
            f16x8 bH[4], bL[4];
            #pragma unroll
            for (int nt = 0; nt < 4; ++nt) {
                const int off = nt * 2048 + (ks * 4 + lg) * 128 + lr * 8;
                bH[nt] = *(const f16x8*)(bb + off);
                bL[nt] = *(const f16x8*)(bb + 8192 + off);
            }
            #pragma unroll
            for (int mt = 0; mt < 2; ++mt)
                #pragma unroll
                for (int nt = 0; nt < 4; ++nt) {
                    acc[mt][nt] = __builtin_amdgcn_mfma_f32_16x16x32_f16(aH[mt][ks], bH[nt], acc[mt][nt], 0, 0, 0);
                    acc[mt][nt] = __builtin_amdgcn_mfma_f32_16x16x32_f16(aH[mt][ks], bL[nt], acc[mt][nt], 0, 0, 0);
                    acc[mt][nt] = __builtin_amdgcn_mfma_f32_16x16x32_f16(aL[mt][ks], bH[nt], acc[mt][nt], 0, 0, 0);
                }
        }

        // epilogue: per-row min over this ctile's 64 cols
        const int ct = ctbase + t;
        const float cn0 = cnorm[ct * 64 + lr];
        const float cn1 = cnorm[ct * 64 + 16 + lr];
        const float cn2 = cnorm[ct * 64 + 32 + lr];
        const float cn3 = cnorm[ct * 64 + 48 + lr];
        #pragma unroll
        for (int mt = 0; mt < 2; ++mt) {
            #pragma unroll
            for (int reg = 0; reg < 4; ++reg) {
                float m0 = fminf(fmaf(-2.0f, acc[mt][0][reg], cn0),
                                 fmaf(-2.0f, acc[mt][1][reg], cn1));
                float m1 = fminf(fmaf(-2.0f, acc[mt][2][reg], cn2),
                                 fmaf(-2.0f, acc[mt][3][reg], cn3));
                float m = fminf(m0, m1);
                m = fminf(m, __shfl_xor(m, 1, 64));
                m = fminf(m, __shfl_xor(m, 2, 64));
                m = fminf(m, __shfl_xor(m, 4, 64));
                m = fminf(m, __shfl_xor(m, 8, 64));
                if (lr == 0)
                    g_ws[(size_t)(rbase + mt * 16 + lg * 4 + reg) * 256 + ct] = m;
            }
        }
        asm volatile("" ::: "memory");
        __builtin_amdgcn_s_barrier();
        cur ^= 1;
    }
}

// ---------------------------------------------------------------------------
// Pass B: exact fp32 refine. For each row: m = min over 256 group minima;
// any group with g <= m + EPS provably contains the exact argmin (and every
// exact tie), since EPS >= 2x the approx error. Re-scan those groups with
// exact fp32 dots; lexicographic (value, index) min = first-index tie-break.
// ---------------------------------------------------------------------------
#define REFINE_EPS 0.05f
__global__ __launch_bounds__(128) void refine_kernel(
    const float* __restrict__ encoded, const float* __restrict__ cb,
    const float* __restrict__ cnorm, const float* __restrict__ g_ws,
    int* __restrict__ idx_ws)
{
    __shared__ float gsm[256];
    __shared__ float xsm[128];
    __shared__ float mpart[2];
    __shared__ float wred[2];
    __shared__ int wredi[2];
    const int row = blockIdx.x;
    const int t = threadIdx.x;

    float g0 = g_ws[(size_t)row * 256 + t];
    float g1 = g_ws[(size_t)row * 256 + 128 + t];
    gsm[t] = g0; gsm[128 + t] = g1;
    xsm[t] = encoded[(size_t)row * 128 + t];

    float m = fminf(g0, g1);
    #pragma unroll
    for (int mask = 1; mask < 64; mask <<= 1) m = fminf(m, __shfl_xor(m, mask, 64));
    if ((t & 63) == 0) mpart[t >> 6] = m;
    __syncthreads();
    const float thr = fminf(mpart[0], mpart[1]) + REFINE_EPS;

    float bv = 3.4e38f; int bi = 0;
    for (int grp = 0; grp < 256; ++grp) {        // ascending: keeps first index
        if (gsm[grp] <= thr) {
            if (t < 64) {
                const int col = grp * 64 + t;
                const float4* cp = (const float4*)(cb + (size_t)col * 128);
                float acc = 0.0f;
                #pragma unroll 8
                for (int z = 0; z < 32; ++z) {
                    float4 c4 = cp[z];
                    acc = fmaf(xsm[4 * z + 0], c4.x, acc);
                    acc = fmaf(xsm[4 * z + 1], c4.y, acc);
                    acc = fmaf(xsm[4 * z + 2], c4.z, acc);
                    acc = fmaf(xsm[4 * z + 3], c4.w, acc);
                }
                float v = fmaf(-2.0f, acc, cnorm[col]);
                if (v < bv) { bv = v; bi = col; }   // strict <: earliest col wins
            }
        }
    }
    #pragma unroll
    for (int mask = 1; mask < 64; mask <<= 1) {
        float ov = __shfl_xor(bv, mask, 64);
        int oi = __shfl_xor(bi, mask, 64);
        if (ov < bv || (ov == bv && oi < bi)) { bv = ov; bi = oi; }
    }
    if ((t & 63) == 0) { wred[t >> 6] = bv; wredi[t >> 6] = bi; }
    __syncthreads();
    if (t == 0) {
        float v1 = wred[1]; int i1 = wredi[1];
        if (v1 < bv || (v1 == bv && i1 < bi)) { bv = v1; bi = i1; }
        idx_ws[row] = min(max(bi, 0), KN - 1);
    }
}

// ---------------------------------------------------------------------------
// Decoder: gather codebook row by refined index, Linear->LN->GELU->Linear,
// per-row reconstruction MSE + global sum (for `scale`).
// ---------------------------------------------------------------------------
__global__ __launch_bounds__(256) void dec_kernel(
    const float* __restrict__ feat, const float* __restrict__ cb,
    const float* __restrict__ W3, const float* __restrict__ b3,
    const float* __restrict__ g2, const float* __restrict__ be2,
    const float* __restrict__ W4, const float* __restrict__ b4,
    const int* __restrict__ idx_ws,
    float* __restrict__ re_ws, float* __restrict__ sum_ws)
{
    __shared__ float qb[8][128];
    __shared__ float dh[8][256];
    __shared__ float red1[4][8];
    __shared__ float red2[4][8];
    __shared__ int idxs[8];
    const int tid = threadIdx.x;
    const int rbase = blockIdx.x * 8;

    if (tid < 8) idxs[tid] = idx_ws[rbase + tid];   // already clamped by refine
    __syncthreads();
    {
        int r = tid >> 5, i = (tid & 31) * 4;
        *((float4*)&qb[r][i]) = *((const float4*)(cb + idxs[r] * 128 + i));
    }
    __syncthreads();

    // GEMM3: t3[r][j], j = tid
    const int j = tid;
    float acc[8];
    {
        float bias = b3[j];
        #pragma unroll
        for (int r = 0; r < 8; ++r) acc[r] = bias;
    }
    for (int k = 0; k < 128; k += 4) {
        float w0 = W3[(k + 0) * 256 + j];
        float w1 = W3[(k + 1) * 256 + j];
        float w2 = W3[(k + 2) * 256 + j];
        float w3v = W3[(k + 3) * 256 + j];
        #pragma unroll
        for (int r = 0; r < 8; ++r) {
            float4 q = *((const float4*)&qb[r][k]);
            acc[r] = fmaf(q.x, w0, acc[r]);
            acc[r] = fmaf(q.y, w1, acc[r]);
            acc[r] = fmaf(q.z, w2, acc[r]);
            acc[r] = fmaf(q.w, w3v, acc[r]);
        }
    }

    // LayerNorm + GELU
    float s1[8], s2[8];
    #pragma unroll
    for (int r = 0; r < 8; ++r) { s1[r] = acc[r]; s2[r] = acc[r] * acc[r]; }
    #pragma unroll
    for (int m = 1; m < 64; m <<= 1) {
        #pragma unroll
        for (int r = 0; r < 8; ++r) {
            s1[r] += __shfl_xor(s1[r], m, 64);
            s2[r] += __shfl_xor(s2[r], m, 64);
        }
    }
    const int wave = tid >> 6, lane = tid & 63;
    if (lane == 0) {
        #pragma unroll
        for (int r = 0; r < 8; ++r) { red1[wave][r] = s1[r]; red2[wave][r] = s2[r]; }
    }
    __syncthreads();
    {
        float gg = g2[j], bb = be2[j];
        #pragma unroll
        for (int r = 0; r < 8; ++r) {
            float sum = red1[0][r] + red1[1][r] + red1[2][r] + red1[3][r];
            float ssq = red2[0][r] + red2[1][r] + red2[2][r] + red2[3][r];
            float mu = sum * (1.0f / 256.0f);
            float var = fmaxf(ssq * (1.0f / 256.0f) - mu * mu, 0.0f);
            float rstd = rsqrtf(var + 1e-5f);
            float t = (acc[r] - mu) * rstd * gg + bb;
            dh[r][j] = 0.5f * t * (1.0f + erff(t * 0.70710678118654752f));
        }
    }
    __syncthreads();

    // GEMM4: rec[r][d] for d = tid and tid+256, then squared error vs features
    float a0[8], a1[8];
    {
        float bias0 = b4[tid], bias1 = b4[tid + 256];
        #pragma unroll
        for (int r = 0; r < 8; ++r) { a0[r] = bias0; a1[r] = bias1; }
    }
    for (int k = 0; k < 256; k += 4) {
        float w00 = W4[(k + 0) * 512 + tid];
        float w01 = W4[(k + 0) * 512 + tid + 256];
        float w10 = W4[(k + 1) * 512 + tid];
        float w11 = W4[(k + 1) * 512 + tid + 256];
        float w20 = W4[(k + 2) * 512 + tid];
        float w21 = W4[(k + 2) * 512 + tid + 256];
        float w30 = W4[(k + 3) * 512 + tid];
        float w31 = W4[(k + 3) * 512 + tid + 256];
        #pragma unroll
        for (int r = 0; r < 8; ++r) {
            float4 h = *((const float4*)&dh[r][k]);
            a0[r] = fmaf(h.x, w00, a0[r]); a1[r] = fmaf(h.x, w01, a1[r]);
            a0[r] = fmaf(h.y, w10, a0[r]); a1[r] = fmaf(h.y, w11, a1[r]);
            a0[r] = fmaf(h.z, w20, a0[r]); a1[r] = fmaf(h.z, w21, a1[r]);
            a0[r] = fmaf(h.w, w30, a0[r]); a1[r] = fmaf(h.w, w31, a1[r]);
        }
    }
    float e[8];
    #pragma unroll
    for (int r = 0; r < 8; ++r) {
        float f0 = feat[(rbase + r) * 512 + tid];
        float f1 = feat[(rbase + r) * 512 + tid + 256];
        float d0 = a0[r] - f0, d1 = a1[r] - f1;
        e[r] = d0 * d0 + d1 * d1;
    }
    #pragma unroll
    for (int m = 1; m < 64; m <<= 1) {
        #pragma unroll
        for (int r = 0; r < 8; ++r) e[r] += __shfl_xor(e[r], m, 64);
    }
    if (lane == 0) {
        #pragma unroll
        for (int r = 0; r < 8; ++r) red1[wave][r] = e[r];
    }
    __syncthreads();
    if (tid < 8) {
        float s = (red1[0][tid] + red1[1][tid] + red1[2][tid] + red1[3][tid]) * (1.0f / 512.0f);
        re_ws[rbase + tid] = s;
        atomicAdd(sum_ws, s);
    }
}

// ---------------------------------------------------------------------------
// Finalize: scale = mean(re)+1e-8; MDL bits; write all 4 fp32 outputs.
// ---------------------------------------------------------------------------
__global__ __launch_bounds__(256) void fin_kernel(
    const float* __restrict__ re_ws, const float* __restrict__ sum_ws,
    const int* __restrict__ idx_ws, float* __restrict__ out)
{
    const int i = blockIdx.x * 256 + threadIdx.x;
    const float scale = (*sum_ws) * (1.0f / 16384.0f) + 1e-8f;
    const float re = re_ws[i];
    const float lp = -fabsf(re) / scale - logf(2.0f * scale);
    const float eb = -lp * 1.4426950408889634f;   // -log_prob / ln(2)
    const float tb = 14.0f + eb;                  // log2(K)=14
    const float ratio = 16384.0f / tb;            // D*32 = 16384
    out[i]             = re;
    out[16384 + i]     = ratio;
    out[2 * 16384 + i] = tb;
    out[3 * 16384 + i] = (float)idx_ws[i];
}

// ---------------------------------------------------------------------------
extern "C" void kernel_launch(void* const* d_in, const int* in_sizes, int n_in,
                              void* d_out, int out_size, void* d_ws, size_t ws_size,
                              hipStream_t stream)
{
    const float* feat = (const float*)d_in[0];
    const float* W1   = (const float*)d_in[1];
    const float* b1   = (const float*)d_in[2];
    const float* g1   = (const float*)d_in[3];
    const float* be1  = (const float*)d_in[4];
    const float* W2   = (const float*)d_in[5];
    const float* b2   = (const float*)d_in[6];
    const float* cb   = (const float*)d_in[7];
    const float* W3   = (const float*)d_in[8];
    const float* b3   = (const float*)d_in[9];
    const float* g2   = (const float*)d_in[10];
    const float* be2  = (const float*)d_in[11];
    const float* W4   = (const float*)d_in[12];
    const float* b4   = (const float*)d_in[13];

    char* ws = (char*)d_ws;
    const size_t MB = 1u << 20;
    float*    encoded = (float*)ws;                            // 8 MB
    _Float16* xh      = (_Float16*)(ws + 8 * MB);              // 4 MB
    _Float16* xl      = (_Float16*)(ws + 12 * MB);             // 4 MB
    _Float16* cpk     = (_Float16*)(ws + 16 * MB);             // 8 MB (256 x 32KB blobs)
    float*    g_ws    = (float*)(ws + 24 * MB);                // 16 MB [16384][256]
    float*    cnorm   = (float*)(ws + 40 * MB);                // 64 KB
    float*    re_ws   = (float*)(ws + 40 * MB + (64u << 10));  // 64 KB
    int*      idx_ws  = (int*)(ws + 40 * MB + (128u << 10));   // 64 KB
    float*    sum_ws  = (float*)(ws + 40 * MB + (192u << 10)); // 4 B

    hipMemsetAsync(sum_ws, 0, sizeof(float), stream);

    hipLaunchKernelGGL(enc_kernel,  dim3(BN / 8), dim3(256), 0, stream,
                       feat, W1, b1, g1, be1, W2, b2, encoded, xh, xl);
    hipLaunchKernelGGL(split_kernel, dim3(KN / 8), dim3(256), 0, stream, cb, cpk, cnorm);
    // 512 blocks = exactly 2/CU, all resident; bid&3 = K-quarter keeps each
    // XCD's packed-B slice (2MB) L2-hot while A frags live in registers.
    hipLaunchKernelGGL(mfma_dist_kernel, dim3(512), dim3(256), 0, stream,
                       xh, xl, cpk, cnorm, g_ws);
    hipLaunchKernelGGL(refine_kernel, dim3(BN), dim3(128), 0, stream,
                       encoded, cb, cnorm, g_ws, idx_ws);
    hipLaunchKernelGGL(dec_kernel,  dim3(BN / 8), dim3(256), 0, stream,
                       feat, cb, W3, b3, g2, be2, W4, b4,
                       idx_ws, re_ws, sum_ws);
    hipLaunchKernelGGL(fin_kernel,  dim3(BN / 256), dim3(256), 0, stream,
                       re_ws, sum_ws, idx_ws, (float*)d_out);
}

// Round 4
// 614.833 us; speedup vs baseline: 1.9420x; 1.0474x over previous
//
#include <hip/hip_runtime.h>
#include <math.h>

// Problem constants (fixed by the reference)
#define BN 16384
#define DN 512
#define KN 16384
#define HN 256
#define ZN 128

typedef _Float16 f16x8 __attribute__((ext_vector_type(8)));
typedef _Float16 f16x4 __attribute__((ext_vector_type(4)));
typedef float f32x4 __attribute__((ext_vector_type(4)));

// ---------------------------------------------------------------------------
// Encoder: features[B,512] -> Linear(512,256) -> LN -> GELU -> Linear(256,128)
// writes encoded[B][128] fp32 AND its f16 hi/lo split. 16 rows/block (halves
// W1/W2 L2 re-streaming vs 8 rows). Per-output fp32 op order unchanged.
// ---------------------------------------------------------------------------
__global__ __launch_bounds__(256) void enc_kernel(
    const float* __restrict__ feat, const float* __restrict__ W1, const float* __restrict__ b1,
    const float* __restrict__ g1, const float* __restrict__ be1,
    const float* __restrict__ W2, const float* __restrict__ b2,
    float* __restrict__ encoded, _Float16* __restrict__ xh, _Float16* __restrict__ xl)
{
    __shared__ float xf[16][512];    // 32KB
    __shared__ float hb[16][256];    // 16KB
    __shared__ float red1[4][16];
    __shared__ float red2[4][16];
    const int tid = threadIdx.x;
    const int rbase = blockIdx.x * 16;

    {   // stage 16 feature rows (8192 fp32 = 32KB), coalesced float4
        const float4* src = (const float4*)(feat + (size_t)rbase * 512);
        float4* dst = (float4*)&xf[0][0];
        #pragma unroll
        for (int i = 0; i < 8; ++i) dst[tid * 8 + i] = src[tid * 8 + i];
    }
    __syncthreads();

    // GEMM1: t1[r][j], j = tid (H=256 columns)
    const int j = tid;
    float acc[16];
    {
        float bias = b1[j];
        #pragma unroll
        for (int r = 0; r < 16; ++r) acc[r] = bias;
    }
    for (int k = 0; k < 512; k += 4) {
        float w0 = W1[(k + 0) * 256 + j];
        float w1 = W1[(k + 1) * 256 + j];
        float w2 = W1[(k + 2) * 256 + j];
        float w3 = W1[(k + 3) * 256 + j];
        #pragma unroll
        for (int r = 0; r < 16; ++r) {
            float4 x = *((const float4*)&xf[r][k]);
            acc[r] = fmaf(x.x, w0, acc[r]);
            acc[r] = fmaf(x.y, w1, acc[r]);
            acc[r] = fmaf(x.z, w2, acc[r]);
            acc[r] = fmaf(x.w, w3, acc[r]);
        }
    }

    // LayerNorm over H=256 (block-wide reduction), then exact GELU
    float s1[16], s2[16];
    #pragma unroll
    for (int r = 0; r < 16; ++r) { s1[r] = acc[r]; s2[r] = acc[r] * acc[r]; }
    #pragma unroll
    for (int m = 1; m < 64; m <<= 1) {
        #pragma unroll
        for (int r = 0; r < 16; ++r) {
            s1[r] += __shfl_xor(s1[r], m, 64);
            s2[r] += __shfl_xor(s2[r], m, 64);
        }
    }
    const int wave = tid >> 6, lane = tid & 63;
    if (lane == 0) {
        #pragma unroll
        for (int r = 0; r < 16; ++r) { red1[wave][r] = s1[r]; red2[wave][r] = s2[r]; }
    }
    __syncthreads();
    {
        float gg = g1[j], bb = be1[j];
        #pragma unroll
        for (int r = 0; r < 16; ++r) {
            float sum = red1[0][r] + red1[1][r] + red1[2][r] + red1[3][r];
            float ssq = red2[0][r] + red2[1][r] + red2[2][r] + red2[3][r];
            float mu = sum * (1.0f / 256.0f);
            float var = fmaxf(ssq * (1.0f / 256.0f) - mu * mu, 0.0f);
            float rstd = rsqrtf(var + 1e-5f);
            float t = (acc[r] - mu) * rstd * gg + bb;
            hb[r][j] = 0.5f * t * (1.0f + erff(t * 0.70710678118654752f));
        }
    }
    __syncthreads();

    // GEMM2: encoded[rh*8+r][j2], j2 = tid&127, row-half by tid>>7
    const int j2 = tid & 127;
    const int rh = tid >> 7;
    float a2[8];
    {
        float bias2 = b2[j2];
        #pragma unroll
        for (int r = 0; r < 8; ++r) a2[r] = bias2;
    }
    for (int k = 0; k < 256; k += 4) {
        float w0 = W2[(k + 0) * 128 + j2];
        float w1 = W2[(k + 1) * 128 + j2];
        float w2v = W2[(k + 2) * 128 + j2];
        float w3 = W2[(k + 3) * 128 + j2];
        #pragma unroll
        for (int r = 0; r < 8; ++r) {
            float4 h = *((const float4*)&hb[rh * 8 + r][k]);
            a2[r] = fmaf(h.x, w0, a2[r]);
            a2[r] = fmaf(h.y, w1, a2[r]);
            a2[r] = fmaf(h.z, w2v, a2[r]);
            a2[r] = fmaf(h.w, w3, a2[r]);
        }
    }
    #pragma unroll
    for (int r = 0; r < 8; ++r) {
        const int idx = (rbase + rh * 8 + r) * 128 + j2;
        const float v = a2[r];
        encoded[idx] = v;
        _Float16 hh = (_Float16)v;
        xh[idx] = hh;
        xl[idx] = (_Float16)(v - (float)hh);
    }
}

// ---------------------------------------------------------------------------
// Split+pack codebook into MFMA-fragment-linear blobs AND compute cnorm.
// Blob layout per ctile c (64 cols): 32KB = [hi/lo][ct(4)][q(16)][lr(16)][8]
// halves. Element (col,k): off = (col>>6)*16384 + hl*8192 + ((col>>4)&3)*2048
//                              + (k>>3)*128 + (col&15)*8 + (k&7).
// ---------------------------------------------------------------------------
__global__ __launch_bounds__(256) void split_kernel(
    const float* __restrict__ cb, _Float16* __restrict__ cpk, float* __restrict__ cnorm)
{
    const int t = threadIdx.x;
    const int col = blockIdx.x * 8 + (t >> 5);
    const int k0 = (t & 31) * 4;
    float4 v = *(const float4*)(cb + (size_t)col * 128 + k0);
    f16x4 h, l;
    h.x = (_Float16)v.x; l.x = (_Float16)(v.x - (float)h.x);
    h.y = (_Float16)v.y; l.y = (_Float16)(v.y - (float)h.y);
    h.z = (_Float16)v.z; l.z = (_Float16)(v.z - (float)h.z);
    h.w = (_Float16)v.w; l.w = (_Float16)(v.w - (float)h.w);
    const size_t base = (size_t)(col >> 6) * 16384 + (size_t)((col >> 4) & 3) * 2048
                      + (size_t)(k0 >> 3) * 128 + (size_t)(col & 15) * 8 + (k0 & 7);
    *(f16x4*)(cpk + base) = h;
    *(f16x4*)(cpk + base + 8192) = l;

    float s = v.x * v.x + v.y * v.y + v.z * v.z + v.w * v.w;
    #pragma unroll
    for (int m = 1; m < 32; m <<= 1) s += __shfl_xor(s, m, 64);
    if ((t & 31) == 0) cnorm[col] = s;
}

// ---------------------------------------------------------------------------
// Pass A: MFMA distance group-minima, SWAPPED operands: D = c x^T.
// score(b,k) = ||c_k||^2 - 2 x_b.c_k via 3-term split f16 (err ~1e-4).
// mfma(cFrag, xFrag): A-row = c-col (lane&15 within ct tile), B-col = x-row
// (lane&15), k = (lane>>4)*8+j for both — identical LDS addressing as the
// verified round-3 kernel; only argument order + epilogue changed.
// D layout: x-row = lane&15 (lr), c-col = (lane>>4)*4 + reg (lg*4+reg) ->
// the min over 64 c-cols is a REGISTER tree (4 ct x 4 reg) + 2 shfl over lg
// (vs 32 shfl before). Epilogue shrinks ~3x; setprio(1) wraps MFMA cluster.
// Block = 4 waves x 32 rows; grid = 128 rb x 4 kq = 512 = 2 blocks/CU.
// B blobs (32KB) double-buffered via linear global_load_lds, counted
// vmcnt(8) so the next blob stays in flight across barriers.
// Output: g_ws[row][ctile] fp32 (row-major, coalesced for refine).
// ---------------------------------------------------------------------------
__global__ __launch_bounds__(256, 2) void mfma_dist_kernel(
    const _Float16* __restrict__ xh, const _Float16* __restrict__ xl,
    const _Float16* __restrict__ cpk, const float* __restrict__ cnorm,
    float* __restrict__ g_ws)
{
    __shared__ __align__(16) _Float16 bs[2][16384];   // 2 x 32KB
    const int tid = threadIdx.x;
    const int w = tid >> 6, l = tid & 63;
    const int lr = l & 15, lg = l >> 4;
    const int q4 = blockIdx.x & 3;          // K-quarter (64 ctiles)
    const int r128 = blockIdx.x >> 2;       // row-block
    const int rbase = r128 * 128 + w * 32;  // this wave's 32 rows
    const int ctbase = q4 * 64;

    // x fragments (B-operand) in registers: [xt][ks], hi+lo (64 VGPRs)
    f16x8 xH[2][4], xL[2][4];
    #pragma unroll
    for (int xt = 0; xt < 2; ++xt) {
        const size_t rowoff = (size_t)(rbase + xt * 16 + lr) * 128;
        #pragma unroll
        for (int ks = 0; ks < 4; ++ks) {
            xH[xt][ks] = *(const f16x8*)(xh + rowoff + ks * 32 + lg * 8);
            xL[xt][ks] = *(const f16x8*)(xl + rowoff + ks * 32 + lg * 8);
        }
    }

    // linear async staging: wave w copies its 8KB of the 32KB blob
    const char* cpkb = (const char*)cpk;
    char* lds0 = (char*)&bs[0][0];
    auto stage = [&](int buf, int ct) {
        const char* src = cpkb + ((size_t)(ctbase + ct) << 15) + (w << 13) + l * 16;
        char* dst = lds0 + (buf << 15) + (w << 13);
        #pragma unroll
        for (int i = 0; i < 8; ++i) {
            __builtin_amdgcn_global_load_lds(
                (const __attribute__((address_space(1))) unsigned int*)(src + i * 1024),
                (__attribute__((address_space(3))) unsigned int*)(dst + i * 1024),
                16, 0, 0);
        }
    };

    stage(0, 0);

    int cur = 0;
    for (int t = 0; t < 64; ++t) {
        if (t < 63) {
            stage(cur ^ 1, t + 1);
            asm volatile("s_waitcnt vmcnt(8)" ::: "memory");  // drain cur, keep next in flight
        } else {
            asm volatile("s_waitcnt vmcnt(0)" ::: "memory");
        }
        __builtin_amdgcn_s_barrier();
        asm volatile("" ::: "memory");

        const _Float16* bb = &bs[cur][0];
        f32x4 acc[4][2];   // [ct][xt]
        #pragma unroll
        for (int ct = 0; ct < 4; ++ct)
            #pragma unroll
            for (int xt = 0; xt < 2; ++xt) {
                f32x4 z = {0.0f, 0.0f, 0.0f, 0.0f};
                acc[ct][xt] = z;
            }

        __builtin_amdgcn_s_setprio(1);
        #pragma unroll
        for (int ks = 0; ks < 4; ++ks) {
            f16x8 cH[4], cL[4];
            #pragma unroll
            for (int ct = 0; ct < 4; ++ct) {
                const int off = ct * 2048 + (ks * 4 + lg) * 128 + lr * 8;
                cH[ct] = *(const f16x8*)(bb + off);
                cL[ct] = *(const f16x8*)(bb + 8192 + off);
            }
            #pragma unroll
            for (int ct = 0; ct < 4; ++ct)
                #pragma unroll
                for (int xt = 0; xt < 2; ++xt) {
                    acc[ct][xt] = __builtin_amdgcn_mfma_f32_16x16x32_f16(cH[ct], xH[xt][ks], acc[ct][xt], 0, 0, 0);
                    acc[ct][xt] = __builtin_amdgcn_mfma_f32_16x16x32_f16(cH[ct], xL[xt][ks], acc[ct][xt], 0, 0, 0);
                    acc[ct][xt] = __builtin_amdgcn_mfma_f32_16x16x32_f16(cL[ct], xH[xt][ks], acc[ct][xt], 0, 0, 0);
                }
        }
        __builtin_amdgcn_s_setprio(0);

        // epilogue: register-tree min over c (4 ct x 4 reg) + 2 shfl over lg
        const int ct64 = (ctbase + t) * 64;
        float4 cn[4];
        #pragma unroll
        for (int ct = 0; ct < 4; ++ct)
            cn[ct] = *(const float4*)(cnorm + ct64 + ct * 16 + lg * 4);
        #pragma unroll
        for (int xt = 0; xt < 2; ++xt) {
            float m = 3.4e38f;
            #pragma unroll
            for (int ct = 0; ct < 4; ++ct) {
                float v0 = fminf(fmaf(-2.0f, acc[ct][xt][0], cn[ct].x),
                                 fmaf(-2.0f, acc[ct][xt][1], cn[ct].y));
                float v1 = fminf(fmaf(-2.0f, acc[ct][xt][2], cn[ct].z),
                                 fmaf(-2.0f, acc[ct][xt][3], cn[ct].w));
                m = fminf(m, fminf(v0, v1));
            }
            m = fminf(m, __shfl_xor(m, 16, 64));
            m = fminf(m, __shfl_xor(m, 32, 64));
            if (lg == 0)
                g_ws[(size_t)(rbase + xt * 16 + lr) * 256 + (ctbase + t)] = m;
        }
        asm volatile("" ::: "memory");
        __builtin_amdgcn_s_barrier();
        cur ^= 1;
    }
}

// ---------------------------------------------------------------------------
// Pass B: exact fp32 refine, ballot-parallel (no serial 256-iter scan).
// thr = min(g) + EPS provably captures the exact argmin and all exact ties
// (EPS >= 2x approx error). Qualifying groups (~1.3/row) extracted from
// per-wave ballots; 256 threads per group dot-phase (64 cols x 4-way K);
// lexicographic (value, index) merges give exact first-index tie-break.
// ---------------------------------------------------------------------------
#define REFINE_EPS 0.05f
__global__ __launch_bounds__(256) void refine_kernel(
    const float* __restrict__ encoded, const float* __restrict__ cb,
    const float* __restrict__ cnorm, const float* __restrict__ g_ws,
    int* __restrict__ idx_ws)
{
    __shared__ float xsm[128];
    __shared__ float mpart[4];
    __shared__ unsigned long long masks[4];
    __shared__ float redv[256];
    __shared__ int redi[256];
    const int row = blockIdx.x;
    const int t = threadIdx.x;
    const int w = t >> 6, lane = t & 63;

    const float g = g_ws[(size_t)row * 256 + t];
    if (t < 128) xsm[t] = encoded[(size_t)row * 128 + t];

    float m = g;
    #pragma unroll
    for (int mk = 1; mk < 64; mk <<= 1) m = fminf(m, __shfl_xor(m, mk, 64));
    if (lane == 0) mpart[w] = m;
    __syncthreads();
    const float thr = fminf(fminf(mpart[0], mpart[1]), fminf(mpart[2], mpart[3])) + REFINE_EPS;

    const unsigned long long bal = __ballot(g <= thr);
    if (lane == 0) masks[w] = bal;
    __syncthreads();

    const int col = t >> 2;     // 0..63: codebook col within group
    const int kp = t & 3;       // k-part: k in [kp*32, kp*32+32)
    float bv = 3.4e38f; int bi = 0;

    for (int wq = 0; wq < 4; ++wq) {
        unsigned long long mm = masks[wq];
        while (mm) {
            const int bit = __ffsll((unsigned long long)mm) - 1;
            mm &= mm - 1;
            const int gcol = (wq * 64 + bit) * 64 + col;
            const float4* cp = (const float4*)(cb + (size_t)gcol * 128 + kp * 32);
            const float4* xp = (const float4*)(xsm + kp * 32);
            float acc = 0.0f;
            #pragma unroll
            for (int i = 0; i < 8; ++i) {
                float4 c4 = cp[i];
                float4 x4 = xp[i];
                acc = fmaf(x4.x, c4.x, acc);
                acc = fmaf(x4.y, c4.y, acc);
                acc = fmaf(x4.z, c4.z, acc);
                acc = fmaf(x4.w, c4.w, acc);
            }
            acc += __shfl_xor(acc, 1, 64);
            acc += __shfl_xor(acc, 2, 64);
            if (kp == 0) {
                const float v = fmaf(-2.0f, acc, cnorm[gcol]);
                if (v < bv || (v == bv && gcol < bi)) { bv = v; bi = gcol; }
            }
        }
    }
    redv[t] = bv; redi[t] = bi;
    __syncthreads();
    if (t < 64) {
        #pragma unroll
        for (int s = 1; s < 4; ++s) {
            float v = redv[t + s * 64]; int ii = redi[t + s * 64];
            if (v < bv || (v == bv && ii < bi)) { bv = v; bi = ii; }
        }
        #pragma unroll
        for (int mk = 1; mk < 64; mk <<= 1) {
            float ov = __shfl_xor(bv, mk, 64);
            int oi = __shfl_xor(bi, mk, 64);
            if (ov < bv || (ov == bv && oi < bi)) { bv = ov; bi = oi; }
        }
        if (t == 0) idx_ws[row] = min(max(bi, 0), KN - 1);
    }
}

// ---------------------------------------------------------------------------
// Decoder: gather codebook row, Linear->LN->GELU->Linear, per-row MSE +
// global sum. 16 rows/block (halves W3/W4 L2 re-streaming).
// ---------------------------------------------------------------------------
__global__ __launch_bounds__(256) void dec_kernel(
    const float* __restrict__ feat, const float* __restrict__ cb,
    const float* __restrict__ W3, const float* __restrict__ b3,
    const float* __restrict__ g2, const float* __restrict__ be2,
    const float* __restrict__ W4, const float* __restrict__ b4,
    const int* __restrict__ idx_ws,
    float* __restrict__ re_ws, float* __restrict__ sum_ws)
{
    __shared__ float qb[16][128];    // 8KB
    __shared__ float dh[16][256];    // 16KB
    __shared__ float red1[4][16];
    __shared__ float red2[4][16];
    __shared__ int idxs[16];
    const int tid = threadIdx.x;
    const int rbase = blockIdx.x * 16;

    if (tid < 16) idxs[tid] = idx_ws[rbase + tid];   // already clamped by refine
    __syncthreads();
    {
        int r = tid >> 4, i = (tid & 15) * 8;
        *((float4*)&qb[r][i])     = *((const float4*)(cb + (size_t)idxs[r] * 128 + i));
        *((float4*)&qb[r][i + 4]) = *((const float4*)(cb + (size_t)idxs[r] * 128 + i + 4));
    }
    __syncthreads();

    // GEMM3: t3[r][j], j = tid
    const int j = tid;
    float acc[16];
    {
        float bias = b3[j];
        #pragma unroll
        for (int r = 0; r < 16; ++r) acc[r] = bias;
    }
    for (int k = 0; k < 128; k += 4) {
        float w0 = W3[(k + 0) * 256 + j];
        float w1 = W3[(k + 1) * 256 + j];
        float w2 = W3[(k + 2) * 256 + j];
        float w3v = W3[(k + 3) * 256 + j];
        #pragma unroll
        for (int r = 0; r < 16; ++r) {
            float4 q = *((const float4*)&qb[r][k]);
            acc[r] = fmaf(q.x, w0, acc[r]);
            acc[r] = fmaf(q.y, w1, acc[r]);
            acc[r] = fmaf(q.z, w2, acc[r]);
            acc[r] = fmaf(q.w, w3v, acc[r]);
        }
    }

    // LayerNorm + GELU
    float s1[16], s2[16];
    #pragma unroll
    for (int r = 0; r < 16; ++r) { s1[r] = acc[r]; s2[r] = acc[r] * acc[r]; }
    #pragma unroll
    for (int m = 1; m < 64; m <<= 1) {
        #pragma unroll
        for (int r = 0; r < 16; ++r) {
            s1[r] += __shfl_xor(s1[r], m, 64);
            s2[r] += __shfl_xor(s2[r], m, 64);
        }
    }
    const int wave = tid >> 6, lane = tid & 63;
    if (lane == 0) {
        #pragma unroll
        for (int r = 0; r < 16; ++r) { red1[wave][r] = s1[r]; red2[wave][r] = s2[r]; }
    }
    __syncthreads();
    {
        float gg = g2[j], bb = be2[j];
        #pragma unroll
        for (int r = 0; r < 16; ++r) {
            float sum = red1[0][r] + red1[1][r] + red1[2][r] + red1[3][r];
            float ssq = red2[0][r] + red2[1][r] + red2[2][r] + red2[3][r];
            float mu = sum * (1.0f / 256.0f);
            float var = fmaxf(ssq * (1.0f / 256.0f) - mu * mu, 0.0f);
            float rstd = rsqrtf(var + 1e-5f);
            float t = (acc[r] - mu) * rstd * gg + bb;
            dh[r][j] = 0.5f * t * (1.0f + erff(t * 0.70710678118654752f));
        }
    }
    __syncthreads();

    // GEMM4: rec[r][d] for d = tid and tid+256, then squared error vs features
    float a0[16], a1[16];
    {
        float bias0 = b4[tid], bias1 = b4[tid + 256];
        #pragma unroll
        for (int r = 0; r < 16; ++r) { a0[r] = bias0; a1[r] = bias1; }
    }
    for (int k = 0; k < 256; k += 4) {
        float w00 = W4[(k + 0) * 512 + tid];
        float w01 = W4[(k + 0) * 512 + tid + 256];
        float w10 = W4[(k + 1) * 512 + tid];
        float w11 = W4[(k + 1) * 512 + tid + 256];
        float w20 = W4[(k + 2) * 512 + tid];
        float w21 = W4[(k + 2) * 512 + tid + 256];
        float w30 = W4[(k + 3) * 512 + tid];
        float w31 = W4[(k + 3) * 512 + tid + 256];
        #pragma unroll
        for (int r = 0; r < 16; ++r) {
            float4 h = *((const float4*)&dh[r][k]);
            a0[r] = fmaf(h.x, w00, a0[r]); a1[r] = fmaf(h.x, w01, a1[r]);
            a0[r] = fmaf(h.y, w10, a0[r]); a1[r] = fmaf(h.y, w11, a1[r]);
            a0[r] = fmaf(h.z, w20, a0[r]); a1[r] = fmaf(h.z, w21, a1[r]);
            a0[r] = fmaf(h.w, w30, a0[r]); a1[r] = fmaf(h.w, w31, a1[r]);
        }
    }
    float e[16];
    #pragma unroll
    for (int r = 0; r < 16; ++r) {
        float f0 = feat[(size_t)(rbase + r) * 512 + tid];
        float f1 = feat[(size_t)(rbase + r) * 512 + tid + 256];
        float d0 = a0[r] - f0, d1 = a1[r] - f1;
        e[r] = d0 * d0 + d1 * d1;
    }
    #pragma unroll
    for (int m = 1; m < 64; m <<= 1) {
        #pragma unroll
        for (int r = 0; r < 16; ++r) e[r] += __shfl_xor(e[r], m, 64);
    }
    if (lane == 0) {
        #pragma unroll
        for (int r = 0; r < 16; ++r) red1[wave][r] = e[r];
    }
    __syncthreads();
    if (tid < 16) {
        float s = (red1[0][tid] + red1[1][tid] + red1[2][tid] + red1[3][tid]) * (1.0f / 512.0f);
        re_ws[rbase + tid] = s;
        atomicAdd(sum_ws, s);
    }
}

// ---------------------------------------------------------------------------
// Finalize: scale = mean(re)+1e-8; MDL bits; write all 4 fp32 outputs.
// ---------------------------------------------------------------------------
__global__ __launch_bounds__(256) void fin_kernel(
    const float* __restrict__ re_ws, const float* __restrict__ sum_ws,
    const int* __restrict__ idx_ws, float* __restrict__ out)
{
    const int i = blockIdx.x * 256 + threadIdx.x;
    const float scale = (*sum_ws) * (1.0f / 16384.0f) + 1e-8f;
    const float re = re_ws[i];
    const float lp = -fabsf(re) / scale - logf(2.0f * scale);
    const float eb = -lp * 1.4426950408889634f;   // -log_prob / ln(2)
    const float tb = 14.0f + eb;                  // log2(K)=14
    const float ratio = 16384.0f / tb;            // D*32 = 16384
    out[i]             = re;
    out[16384 + i]     = ratio;
    out[2 * 16384 + i] = tb;
    out[3 * 16384 + i] = (float)idx_ws[i];
}

// ---------------------------------------------------------------------------
extern "C" void kernel_launch(void* const* d_in, const int* in_sizes, int n_in,
                              void* d_out, int out_size, void* d_ws, size_t ws_size,
                              hipStream_t stream)
{
    const float* feat = (const float*)d_in[0];
    const float* W1   = (const float*)d_in[1];
    const float* b1   = (const float*)d_in[2];
    const float* g1   = (const float*)d_in[3];
    const float* be1  = (const float*)d_in[4];
    const float* W2   = (const float*)d_in[5];
    const float* b2   = (const float*)d_in[6];
    const float* cb   = (const float*)d_in[7];
    const float* W3   = (const float*)d_in[8];
    const float* b3   = (const float*)d_in[9];
    const float* g2   = (const float*)d_in[10];
    const float* be2  = (const float*)d_in[11];
    const float* W4   = (const float*)d_in[12];
    const float* b4   = (const float*)d_in[13];

    char* ws = (char*)d_ws;
    const size_t MB = 1u << 20;
    float*    encoded = (float*)ws;                            // 8 MB
    _Float16* xh      = (_Float16*)(ws + 8 * MB);              // 4 MB
    _Float16* xl      = (_Float16*)(ws + 12 * MB);             // 4 MB
    _Float16* cpk     = (_Float16*)(ws + 16 * MB);             // 8 MB (256 x 32KB blobs)
    float*    g_ws    = (float*)(ws + 24 * MB);                // 16 MB [16384][256]
    float*    cnorm   = (float*)(ws + 40 * MB);                // 64 KB
    float*    re_ws   = (float*)(ws + 40 * MB + (64u << 10));  // 64 KB
    int*      idx_ws  = (int*)(ws + 40 * MB + (128u << 10));   // 64 KB
    float*    sum_ws  = (float*)(ws + 40 * MB + (192u << 10)); // 4 B

    hipMemsetAsync(sum_ws, 0, sizeof(float), stream);

    hipLaunchKernelGGL(enc_kernel,  dim3(BN / 16), dim3(256), 0, stream,
                       feat, W1, b1, g1, be1, W2, b2, encoded, xh, xl);
    hipLaunchKernelGGL(split_kernel, dim3(KN / 8), dim3(256), 0, stream, cb, cpk, cnorm);
    // 512 blocks = exactly 2/CU, all resident; bid&3 = K-quarter keeps each
    // XCD's packed-B slice (2MB) L2-hot while x frags live in registers.
    hipLaunchKernelGGL(mfma_dist_kernel, dim3(512), dim3(256), 0, stream,
                       xh, xl, cpk, cnorm, g_ws);
    hipLaunchKernelGGL(refine_kernel, dim3(BN), dim3(256), 0, stream,
                       encoded, cb, cnorm, g_ws, idx_ws);
    hipLaunchKernelGGL(dec_kernel,  dim3(BN / 16), dim3(256), 0, stream,
                       feat, cb, W3, b3, g2, be2, W4, b4,
                       idx_ws, re_ws, sum_ws);
    hipLaunchKernelGGL(fin_kernel,  dim3(BN / 256), dim3(256), 0, stream,
                       re_ws, sum_ws, idx_ws, (float*)d_out);
}